// Round 1
// baseline (1105.870 us; speedup 1.0000x reference)
//
#include <hip/hip_runtime.h>
#include <cstdint>
#include <cstddef>

#define NN 100000
#define EE 1000000
#define EPSF 1e-5f

__device__ __forceinline__ void fatomic(float* p, float v) { unsafeAtomicAdd(p, v); }

// ---- degree histogram (both relations) ----
__global__ __launch_bounds__(256) void k_degree(const int* __restrict__ pe,
                                                const int* __restrict__ ne,
                                                int* __restrict__ degP,
                                                int* __restrict__ degN) {
    int t = blockIdx.x * 256 + threadIdx.x;
    if (t < EE) {
        atomicAdd(&degP[pe[EE + t]], 1);
    } else if (t < 2 * EE) {
        int e = t - EE;
        atomicAdd(&degN[ne[EE + e]], 1);
    }
}

// ---- raw-feature aggregation, 64-dim (conv1) ----
__global__ __launch_bounds__(256) void k_agg64(const float* __restrict__ x,
                                               const int* __restrict__ pe,
                                               const int* __restrict__ ne,
                                               float* __restrict__ aggP,
                                               float* __restrict__ aggN) {
    unsigned t = blockIdx.x * 256u + threadIdx.x;
    unsigned e = t >> 6;
    int f = t & 63;
    const int* ed;
    float* agg;
    if (e < EE) { ed = pe; agg = aggP; }
    else { e -= EE; if (e >= EE) return; ed = ne; agg = aggN; }
    int src = ed[e], dst = ed[EE + e];
    fatomic(&agg[(size_t)dst * 64 + f], x[(size_t)src * 64 + f]);
}

// ---- raw-feature aggregation, 32-dim (conv2) ----
__global__ __launch_bounds__(256) void k_agg32(const float* __restrict__ x,
                                               const int* __restrict__ pe,
                                               const int* __restrict__ ne,
                                               float* __restrict__ aggP,
                                               float* __restrict__ aggN) {
    unsigned t = blockIdx.x * 256u + threadIdx.x;
    unsigned e = t >> 5;
    int f = t & 31;
    const int* ed;
    float* agg;
    if (e < EE) { ed = pe; agg = aggP; }
    else { e -= EE; if (e >= EE) return; ed = ne; agg = aggN; }
    int src = ed[e], dst = ed[EE + e];
    fatomic(&agg[(size_t)dst * 32 + f], x[(size_t)src * 32 + f]);
}

// ---- conv1 linear: z1 = tanh(aggP@Wp + degP*bp + aggN@Wn + degN*bn + x@Ws + bs) ----
__global__ __launch_bounds__(256) void k_conv1(const float* __restrict__ aggP,
                                               const float* __restrict__ aggN,
                                               const float* __restrict__ x,
                                               const int* __restrict__ degP,
                                               const int* __restrict__ degN,
                                               const float* __restrict__ Wp, const float* __restrict__ bp,
                                               const float* __restrict__ Wn, const float* __restrict__ bn,
                                               const float* __restrict__ Ws, const float* __restrict__ bs,
                                               float* __restrict__ z1) {
    __shared__ float sWp[64 * 32], sWn[64 * 32], sWs[64 * 32];
    for (int i = threadIdx.x; i < 64 * 32; i += 256) {
        sWp[i] = Wp[i]; sWn[i] = Wn[i]; sWs[i] = Ws[i];
    }
    __syncthreads();
    int j = threadIdx.x & 31;
    int r = threadIdx.x >> 5;  // 0..7
    float bpj = bp[j], bnj = bn[j], bsj = bs[j];
    for (int n = blockIdx.x * 8 + r; n < NN; n += 2048 * 8) {
        const float* ap = aggP + (size_t)n * 64;
        const float* an = aggN + (size_t)n * 64;
        const float* xs = x + (size_t)n * 64;
        float acc = (float)degP[n] * bpj + (float)degN[n] * bnj + bsj;
        #pragma unroll
        for (int k = 0; k < 64; k++)
            acc += ap[k] * sWp[k * 32 + j] + an[k] * sWn[k * 32 + j] + xs[k] * sWs[k * 32 + j];
        z1[(size_t)n * 32 + j] = tanhf(acc);
    }
}

// ---- conv2 linear: 32 -> 32 ----
__global__ __launch_bounds__(256) void k_conv2(const float* __restrict__ aggP,
                                               const float* __restrict__ aggN,
                                               const float* __restrict__ zin,
                                               const int* __restrict__ degP,
                                               const int* __restrict__ degN,
                                               const float* __restrict__ Wp, const float* __restrict__ bp,
                                               const float* __restrict__ Wn, const float* __restrict__ bn,
                                               const float* __restrict__ Ws, const float* __restrict__ bs,
                                               float* __restrict__ z2) {
    __shared__ float sWp[32 * 32], sWn[32 * 32], sWs[32 * 32];
    for (int i = threadIdx.x; i < 32 * 32; i += 256) {
        sWp[i] = Wp[i]; sWn[i] = Wn[i]; sWs[i] = Ws[i];
    }
    __syncthreads();
    int j = threadIdx.x & 31;
    int r = threadIdx.x >> 5;
    float bpj = bp[j], bnj = bn[j], bsj = bs[j];
    for (int n = blockIdx.x * 8 + r; n < NN; n += 2048 * 8) {
        const float* ap = aggP + (size_t)n * 32;
        const float* an = aggN + (size_t)n * 32;
        const float* zs = zin + (size_t)n * 32;
        float acc = (float)degP[n] * bpj + (float)degN[n] * bnj + bsj;
        #pragma unroll
        for (int k = 0; k < 32; k++)
            acc += ap[k] * sWp[k * 32 + j] + an[k] * sWn[k * 32 + j] + zs[k] * sWs[k * 32 + j];
        z2[(size_t)n * 32 + j] = tanhf(acc);
    }
}

// ---- z = tanh(z2 @ w_W + w_b): 32 -> 64 (writes output 0) ----
__global__ __launch_bounds__(256) void k_wlin(const float* __restrict__ z2,
                                              const float* __restrict__ W,
                                              const float* __restrict__ b,
                                              float* __restrict__ z) {
    int j = threadIdx.x & 63;
    int r = threadIdx.x >> 6;  // 0..3
    float w[32];
    #pragma unroll
    for (int k = 0; k < 32; k++) w[k] = W[k * 64 + j];
    float bj = b[j];
    for (int n = blockIdx.x * 4 + r; n < NN; n += 2048 * 4) {
        const float* zr = z2 + (size_t)n * 32;
        float s = bj;
        #pragma unroll
        for (int k = 0; k < 32; k++) s += zr[k] * w[k];
        z[(size_t)n * 64 + j] = tanhf(s);
    }
}

// ---- t1 = z @ m1_W + m1_b, accumulate column sum / sumsq ----
__global__ __launch_bounds__(256) void k_mlp1(const float* __restrict__ z,
                                              const float* __restrict__ W,
                                              const float* __restrict__ b,
                                              float* __restrict__ t1,
                                              float* __restrict__ colsum,
                                              float* __restrict__ colsq) {
    int j = threadIdx.x & 63;
    int r = threadIdx.x >> 6;
    float w[64];
    #pragma unroll
    for (int k = 0; k < 64; k++) w[k] = W[k * 64 + j];
    float bj = b[j];
    float lsum = 0.f, lsq = 0.f;
    for (int n = blockIdx.x * 4 + r; n < NN; n += 2048 * 4) {
        const float* zr = z + (size_t)n * 64;
        float s = bj;
        #pragma unroll
        for (int k = 0; k < 64; k++) s += zr[k] * w[k];
        t1[(size_t)n * 64 + j] = s;
        lsum += s; lsq += s * s;
    }
    __shared__ float red[256], red2[256];
    red[threadIdx.x] = lsum; red2[threadIdx.x] = lsq;
    __syncthreads();
    if (threadIdx.x < 64) {
        float a = red[threadIdx.x] + red[threadIdx.x + 64] + red[threadIdx.x + 128] + red[threadIdx.x + 192];
        float q = red2[threadIdx.x] + red2[threadIdx.x + 64] + red2[threadIdx.x + 128] + red2[threadIdx.x + 192];
        fatomic(&colsum[threadIdx.x], a);
        fatomic(&colsq[threadIdx.x], q);
    }
}

// ---- BN stats -> affine coefficients a, c (h_norm = t*a + c) ----
__global__ void k_bnstats(const float* __restrict__ colsum, const float* __restrict__ colsq,
                          const float* __restrict__ g, const float* __restrict__ beta,
                          float* __restrict__ a, float* __restrict__ c) {
    int j = threadIdx.x;
    if (j < 64) {
        float m = colsum[j] * (1.f / NN);
        float v = colsq[j] * (1.f / NN) - m * m;
        float aj = g[j] * rsqrtf(v + EPSF);
        a[j] = aj;
        c[j] = beta[j] - m * aj;
    }
}

// ---- t2 = relu(t1*a1+c1) @ m2_W + m2_b, accumulate stats ----
__global__ __launch_bounds__(256) void k_mlp2(const float* __restrict__ t1,
                                              const float* __restrict__ a1,
                                              const float* __restrict__ c1,
                                              const float* __restrict__ W,
                                              const float* __restrict__ b,
                                              float* __restrict__ t2,
                                              float* __restrict__ colsum,
                                              float* __restrict__ colsq) {
    __shared__ float sa[64], sc[64];
    if (threadIdx.x < 64) { sa[threadIdx.x] = a1[threadIdx.x]; sc[threadIdx.x] = c1[threadIdx.x]; }
    int j = threadIdx.x & 63;
    int r = threadIdx.x >> 6;
    float w[64];
    #pragma unroll
    for (int k = 0; k < 64; k++) w[k] = W[k * 64 + j];
    float bj = b[j];
    __syncthreads();
    float lsum = 0.f, lsq = 0.f;
    for (int n = blockIdx.x * 4 + r; n < NN; n += 2048 * 4) {
        const float* tr = t1 + (size_t)n * 64;
        float s = bj;
        #pragma unroll
        for (int k = 0; k < 64; k++) {
            float h = fmaxf(tr[k] * sa[k] + sc[k], 0.f);
            s += h * w[k];
        }
        t2[(size_t)n * 64 + j] = s;
        lsum += s; lsq += s * s;
    }
    __shared__ float red[256], red2[256];
    red[threadIdx.x] = lsum; red2[threadIdx.x] = lsq;
    __syncthreads();
    if (threadIdx.x < 64) {
        float a = red[threadIdx.x] + red[threadIdx.x + 64] + red[threadIdx.x + 128] + red[threadIdx.x + 192];
        float q = red2[threadIdx.x] + red2[threadIdx.x + 64] + red2[threadIdx.x + 128] + red2[threadIdx.x + 192];
        fatomic(&colsum[threadIdx.x], a);
        fatomic(&colsq[threadIdx.x], q);
    }
}

// ---- prob = sigmoid(relu(t2*a2+c2) @ m3_W + m3_b) ----
__global__ __launch_bounds__(256) void k_mlp3(const float* __restrict__ t2,
                                              const float* __restrict__ a2,
                                              const float* __restrict__ c2,
                                              const float* __restrict__ W3,
                                              const float* __restrict__ b3,
                                              float* __restrict__ prob) {
    int j = threadIdx.x & 63;
    int r = threadIdx.x >> 6;
    float aj = a2[j], cj = c2[j], wj = W3[j], bb = b3[0];
    for (int n = blockIdx.x * 4 + r; n < NN; n += 2048 * 4) {
        float h = fmaxf(t2[(size_t)n * 64 + j] * aj + cj, 0.f) * wj;
        #pragma unroll
        for (int off = 32; off > 0; off >>= 1) h += __shfl_xor(h, off, 64);
        if (j == 0) prob[n] = 1.f / (1.f + expf(-(h + bb)));
    }
}

extern "C" void kernel_launch(void* const* d_in, const int* in_sizes, int n_in,
                              void* d_out, int out_size, void* d_ws, size_t ws_size,
                              hipStream_t stream) {
    const float* init_emb = (const float*)d_in[0];
    const int* pe = (const int*)d_in[1];
    const int* ne = (const int*)d_in[2];
    const float* c1_Wp = (const float*)d_in[3];  const float* c1_bp = (const float*)d_in[4];
    const float* c1_Wn = (const float*)d_in[5];  const float* c1_bn = (const float*)d_in[6];
    const float* c1_Ws = (const float*)d_in[7];  const float* c1_bs = (const float*)d_in[8];
    const float* c2_Wp = (const float*)d_in[9];  const float* c2_bp = (const float*)d_in[10];
    const float* c2_Wn = (const float*)d_in[11]; const float* c2_bn = (const float*)d_in[12];
    const float* c2_Ws = (const float*)d_in[13]; const float* c2_bs = (const float*)d_in[14];
    const float* w_W = (const float*)d_in[15];   const float* w_b = (const float*)d_in[16];
    const float* m1_W = (const float*)d_in[17];  const float* m1_b = (const float*)d_in[18];
    const float* g1 = (const float*)d_in[19];    const float* b1 = (const float*)d_in[20];
    const float* m2_W = (const float*)d_in[21];  const float* m2_b = (const float*)d_in[22];
    const float* g2 = (const float*)d_in[23];    const float* b2 = (const float*)d_in[24];
    const float* m3_W = (const float*)d_in[25];  const float* m3_b = (const float*)d_in[26];

    // ---- workspace arena ----
    size_t off = 0;
    auto alloc = [&](size_t bytes) -> void* {
        void* r = (char*)d_ws + off;
        off += (bytes + 255) & ~(size_t)255;
        return r;
    };
    int*   degP  = (int*)alloc((size_t)NN * 4);
    int*   degN  = (int*)alloc((size_t)NN * 4);
    float* sums  = (float*)alloc(256 * 4);              // colsum1, colsq1, colsum2, colsq2
    float* aggP1 = (float*)alloc((size_t)NN * 64 * 4);
    float* aggN1 = (float*)alloc((size_t)NN * 64 * 4);
    float* aggP2 = (float*)alloc((size_t)NN * 32 * 4);
    float* aggN2 = (float*)alloc((size_t)NN * 32 * 4);
    size_t zero_bytes = off;                            // everything above must be zeroed
    float* abc = (float*)alloc(256 * 4);                // a1, c1, a2, c2
    float* z1  = (float*)alloc((size_t)NN * 32 * 4);
    float* z2  = (float*)alloc((size_t)NN * 32 * 4);
    float* t1  = aggP1;  // dead after conv1 -> reuse
    float* t2  = aggN1;  // dead after conv1 -> reuse

    float* z_out = (float*)d_out;                       // [N,64]
    float* prob  = (float*)d_out + (size_t)NN * 64;     // [N,1]

    hipMemsetAsync(d_ws, 0, zero_bytes, stream);

    k_degree<<<(2 * EE + 255) / 256, 256, 0, stream>>>(pe, ne, degP, degN);
    k_agg64<<<(2 * EE * 64) / 256, 256, 0, stream>>>(init_emb, pe, ne, aggP1, aggN1);
    k_conv1<<<2048, 256, 0, stream>>>(aggP1, aggN1, init_emb, degP, degN,
                                      c1_Wp, c1_bp, c1_Wn, c1_bn, c1_Ws, c1_bs, z1);
    k_agg32<<<(2 * EE * 32) / 256, 256, 0, stream>>>(z1, pe, ne, aggP2, aggN2);
    k_conv2<<<2048, 256, 0, stream>>>(aggP2, aggN2, z1, degP, degN,
                                      c2_Wp, c2_bp, c2_Wn, c2_bn, c2_Ws, c2_bs, z2);
    k_wlin<<<2048, 256, 0, stream>>>(z2, w_W, w_b, z_out);
    k_mlp1<<<2048, 256, 0, stream>>>(z_out, m1_W, m1_b, t1, sums + 0, sums + 64);
    k_bnstats<<<1, 64, 0, stream>>>(sums + 0, sums + 64, g1, b1, abc + 0, abc + 64);
    k_mlp2<<<2048, 256, 0, stream>>>(t1, abc + 0, abc + 64, m2_W, m2_b, t2, sums + 128, sums + 192);
    k_bnstats<<<1, 64, 0, stream>>>(sums + 128, sums + 192, g2, b2, abc + 128, abc + 192);
    k_mlp3<<<2048, 256, 0, stream>>>(t2, abc + 128, abc + 192, m3_W, m3_b, prob);
}

// Round 2
// 893.212 us; speedup vs baseline: 1.2381x; 1.2381x over previous
//
#include <hip/hip_runtime.h>
#include <cstdint>
#include <cstddef>

#define NN 100000
#define EE 1000000
#define EPSF 1e-5f

__device__ __forceinline__ void fatomic(float* p, float v) { unsafeAtomicAdd(p, v); }

// ---- degree histogram (both relations), int atomics ----
__global__ __launch_bounds__(256) void k_degree(const int* __restrict__ pe,
                                                const int* __restrict__ ne,
                                                int* __restrict__ degP,
                                                int* __restrict__ degN) {
    int t = blockIdx.x * 256 + threadIdx.x;
    if (t < EE) {
        atomicAdd(&degP[pe[EE + t]], 1);
    } else if (t < 2 * EE) {
        int e = t - EE;
        atomicAdd(&degN[ne[EE + e]], 1);
    }
}

// ---- exclusive scan of both degree arrays -> row pointers (single block) ----
__global__ __launch_bounds__(1024) void k_scan(const int* __restrict__ degP,
                                               const int* __restrict__ degN,
                                               int* __restrict__ rpP,
                                               int* __restrict__ rpN) {
    __shared__ int part[1024];
    int t = threadIdx.x;
    const int CH = 98;  // 1024*98 >= 100000
    for (int ph = 0; ph < 2; ph++) {
        const int* deg = ph ? degN : degP;
        int* rp = ph ? rpN : rpP;
        int lo = t * CH, hi = min(lo + CH, NN);
        int s = 0;
        for (int i = lo; i < hi; i++) s += deg[i];
        part[t] = s;
        __syncthreads();
        for (int off = 1; off < 1024; off <<= 1) {
            int v = (t >= off) ? part[t - off] : 0;
            __syncthreads();
            part[t] += v;
            __syncthreads();
        }
        int run = (t == 0) ? 0 : part[t - 1];
        for (int i = lo; i < hi; i++) { rp[i] = run; run += deg[i]; }
        if (t == 1023) rp[NN] = part[1023];
        __syncthreads();
    }
}

// ---- scatter edges into CSR (src lists grouped by dst) ----
__global__ __launch_bounds__(256) void k_scatter(const int* __restrict__ pe,
                                                 const int* __restrict__ ne,
                                                 const int* __restrict__ rpP,
                                                 const int* __restrict__ rpN,
                                                 int* __restrict__ curP,
                                                 int* __restrict__ curN,
                                                 int* __restrict__ csrP,
                                                 int* __restrict__ csrN) {
    int t = blockIdx.x * 256 + threadIdx.x;
    if (t < EE) {
        int dst = pe[EE + t];
        int slot = atomicAdd(&curP[dst], 1);
        csrP[rpP[dst] + slot] = pe[t];
    } else if (t < 2 * EE) {
        int e = t - EE;
        int dst = ne[EE + e];
        int slot = atomicAdd(&curN[dst], 1);
        csrN[rpN[dst] + slot] = ne[e];
    }
}

// ---- pre-transform 64->32 x3: xp=x@Wp, xn=x@Wn, xs=x@Ws ----
__global__ __launch_bounds__(256) void k_xf1(const float* __restrict__ x,
                                             const float* __restrict__ Wp,
                                             const float* __restrict__ Wn,
                                             const float* __restrict__ Ws,
                                             float* __restrict__ xp,
                                             float* __restrict__ xn,
                                             float* __restrict__ xs) {
    __shared__ float sWp[64 * 32], sWn[64 * 32], sWs[64 * 32];
    for (int i = threadIdx.x; i < 64 * 32; i += 256) { sWp[i] = Wp[i]; sWn[i] = Wn[i]; sWs[i] = Ws[i]; }
    __syncthreads();
    int lane = threadIdx.x & 63;
    int j = lane & 31;
    int half = lane >> 5;
    int wid = (blockIdx.x * 256 + threadIdx.x) >> 6;
    const int nw = (2048 * 256) >> 6;
    for (int p = wid; 2 * p < NN; p += nw) {
        int n = 2 * p + half;
        float vlo = x[(size_t)n * 64 + j];
        float vhi = x[(size_t)n * 64 + 32 + j];
        float ap = 0.f, an = 0.f, as = 0.f;
        #pragma unroll
        for (int k = 0; k < 64; k++) {
            float xv = (k < 32) ? __shfl(vlo, k, 32) : __shfl(vhi, k - 32, 32);
            ap += xv * sWp[k * 32 + j];
            an += xv * sWn[k * 32 + j];
            as += xv * sWs[k * 32 + j];
        }
        xp[(size_t)n * 32 + j] = ap;
        xn[(size_t)n * 32 + j] = an;
        xs[(size_t)n * 32 + j] = as;
    }
}

// ---- pre-transform 32->32 x3 ----
__global__ __launch_bounds__(256) void k_xf2(const float* __restrict__ z,
                                             const float* __restrict__ Wp,
                                             const float* __restrict__ Wn,
                                             const float* __restrict__ Ws,
                                             float* __restrict__ xp,
                                             float* __restrict__ xn,
                                             float* __restrict__ xs) {
    __shared__ float sWp[32 * 32], sWn[32 * 32], sWs[32 * 32];
    for (int i = threadIdx.x; i < 32 * 32; i += 256) { sWp[i] = Wp[i]; sWn[i] = Wn[i]; sWs[i] = Ws[i]; }
    __syncthreads();
    int lane = threadIdx.x & 63;
    int j = lane & 31;
    int half = lane >> 5;
    int wid = (blockIdx.x * 256 + threadIdx.x) >> 6;
    const int nw = (2048 * 256) >> 6;
    for (int p = wid; 2 * p < NN; p += nw) {
        int n = 2 * p + half;
        float v = z[(size_t)n * 32 + j];
        float ap = 0.f, an = 0.f, as = 0.f;
        #pragma unroll
        for (int k = 0; k < 32; k++) {
            float xv = __shfl(v, k, 32);
            ap += xv * sWp[k * 32 + j];
            an += xv * sWn[k * 32 + j];
            as += xv * sWs[k * 32 + j];
        }
        xp[(size_t)n * 32 + j] = ap;
        xn[(size_t)n * 32 + j] = an;
        xs[(size_t)n * 32 + j] = as;
    }
}

// ---- accumulate one relation's neighbors ----
__device__ __forceinline__ float pull_rel(const float* __restrict__ xsrc,
                                          const int* __restrict__ csr,
                                          int b0, int b1, int j, float acc) {
    for (int base = b0; base < b1; base += 32) {
        int rem = b1 - base;
        int cnt = min(rem, 32);
        int idx = (j < rem) ? csr[base + j] : 0;
        int i = 0;
        for (; i + 4 <= cnt; i += 4) {
            int s0 = __shfl(idx, i, 32);
            int s1 = __shfl(idx, i + 1, 32);
            int s2 = __shfl(idx, i + 2, 32);
            int s3 = __shfl(idx, i + 3, 32);
            float v0 = xsrc[(size_t)s0 * 32 + j];
            float v1 = xsrc[(size_t)s1 * 32 + j];
            float v2 = xsrc[(size_t)s2 * 32 + j];
            float v3 = xsrc[(size_t)s3 * 32 + j];
            acc += v0; acc += v1; acc += v2; acc += v3;
        }
        for (; i < cnt; i++) {
            int s = __shfl(idx, i, 32);
            acc += xsrc[(size_t)s * 32 + j];
        }
    }
    return acc;
}

// ---- pull aggregation + combine + tanh: out = tanh(sumP(xp) + sumN(xn) + degP*bp + degN*bn + xs + bs) ----
__global__ __launch_bounds__(256) void k_pull(const float* __restrict__ xp,
                                              const float* __restrict__ xn,
                                              const float* __restrict__ xs,
                                              const int* __restrict__ rpP,
                                              const int* __restrict__ csrP,
                                              const int* __restrict__ rpN,
                                              const int* __restrict__ csrN,
                                              const float* __restrict__ bp,
                                              const float* __restrict__ bn,
                                              const float* __restrict__ bs,
                                              float* __restrict__ out) {
    int j = threadIdx.x & 31;
    int hw = (blockIdx.x * 256 + threadIdx.x) >> 5;
    const int nhw = (2048 * 256) >> 5;
    float bpj = bp[j], bnj = bn[j], bsj = bs[j];
    for (int n = hw; n < NN; n += nhw) {
        int p0 = rpP[n], p1 = rpP[n + 1];
        int n0 = rpN[n], n1 = rpN[n + 1];
        float acc = xs[(size_t)n * 32 + j] + bsj
                  + (float)(p1 - p0) * bpj + (float)(n1 - n0) * bnj;
        acc = pull_rel(xp, csrP, p0, p1, j, acc);
        acc = pull_rel(xn, csrN, n0, n1, j, acc);
        out[(size_t)n * 32 + j] = tanhf(acc);
    }
}

// ---- fused: z = tanh(z2 @ w_W + w_b)  (output 0), t1 = z @ m1_W + m1_b, BN stats ----
__global__ __launch_bounds__(256) void k_wlin_mlp1(const float* __restrict__ z2,
                                                   const float* __restrict__ Wl,
                                                   const float* __restrict__ bl,
                                                   const float* __restrict__ W1,
                                                   const float* __restrict__ b1_,
                                                   float* __restrict__ z,
                                                   float* __restrict__ t1,
                                                   float* __restrict__ colsum,
                                                   float* __restrict__ colsq) {
    int lane = threadIdx.x & 63;
    int wv = threadIdx.x >> 6;
    float wl[32];
    #pragma unroll
    for (int k = 0; k < 32; k++) wl[k] = Wl[k * 64 + lane];
    float w1[64];
    #pragma unroll
    for (int k = 0; k < 64; k++) w1[k] = W1[k * 64 + lane];
    float blj = bl[lane], b1j = b1_[lane];
    float lsum = 0.f, lsq = 0.f;
    for (int n = blockIdx.x * 4 + wv; n < NN; n += 2048 * 4) {
        float v = z2[(size_t)n * 32 + (lane & 31)];
        float s = blj;
        #pragma unroll
        for (int k = 0; k < 32; k++) s += __shfl(v, k, 64) * wl[k];
        float zv = tanhf(s);
        z[(size_t)n * 64 + lane] = zv;
        float t = b1j;
        #pragma unroll
        for (int k = 0; k < 64; k++) t += __shfl(zv, k, 64) * w1[k];
        t1[(size_t)n * 64 + lane] = t;
        lsum += t; lsq += t * t;
    }
    __shared__ float red[256], red2[256];
    red[threadIdx.x] = lsum; red2[threadIdx.x] = lsq;
    __syncthreads();
    if (threadIdx.x < 64) {
        float a = red[threadIdx.x] + red[threadIdx.x + 64] + red[threadIdx.x + 128] + red[threadIdx.x + 192];
        float q = red2[threadIdx.x] + red2[threadIdx.x + 64] + red2[threadIdx.x + 128] + red2[threadIdx.x + 192];
        fatomic(&colsum[threadIdx.x], a);
        fatomic(&colsq[threadIdx.x], q);
    }
}

// ---- BN stats -> affine coefficients a, c (h_norm = t*a + c) ----
__global__ void k_bnstats(const float* __restrict__ colsum, const float* __restrict__ colsq,
                          const float* __restrict__ g, const float* __restrict__ beta,
                          float* __restrict__ a, float* __restrict__ c) {
    int j = threadIdx.x;
    if (j < 64) {
        float m = colsum[j] * (1.f / NN);
        float v = colsq[j] * (1.f / NN) - m * m;
        float aj = g[j] * rsqrtf(v + EPSF);
        a[j] = aj;
        c[j] = beta[j] - m * aj;
    }
}

// ---- t2 = relu(t1*a1+c1) @ m2_W + m2_b, accumulate stats ----
__global__ __launch_bounds__(256) void k_mlp2(const float* __restrict__ t1,
                                              const float* __restrict__ a1,
                                              const float* __restrict__ c1,
                                              const float* __restrict__ W,
                                              const float* __restrict__ b,
                                              float* __restrict__ t2,
                                              float* __restrict__ colsum,
                                              float* __restrict__ colsq) {
    int lane = threadIdx.x & 63;
    int wv = threadIdx.x >> 6;
    float w[64];
    #pragma unroll
    for (int k = 0; k < 64; k++) w[k] = W[k * 64 + lane];
    float bj = b[lane];
    float sa = a1[lane], sc = c1[lane];
    float lsum = 0.f, lsq = 0.f;
    for (int n = blockIdx.x * 4 + wv; n < NN; n += 2048 * 4) {
        float v = t1[(size_t)n * 64 + lane];
        float h = fmaxf(v * sa + sc, 0.f);
        float s = bj;
        #pragma unroll
        for (int k = 0; k < 64; k++) s += __shfl(h, k, 64) * w[k];
        t2[(size_t)n * 64 + lane] = s;
        lsum += s; lsq += s * s;
    }
    __shared__ float red[256], red2[256];
    red[threadIdx.x] = lsum; red2[threadIdx.x] = lsq;
    __syncthreads();
    if (threadIdx.x < 64) {
        float a = red[threadIdx.x] + red[threadIdx.x + 64] + red[threadIdx.x + 128] + red[threadIdx.x + 192];
        float q = red2[threadIdx.x] + red2[threadIdx.x + 64] + red2[threadIdx.x + 128] + red2[threadIdx.x + 192];
        fatomic(&colsum[threadIdx.x], a);
        fatomic(&colsq[threadIdx.x], q);
    }
}

// ---- prob = sigmoid(relu(t2*a2+c2) @ m3_W + m3_b) ----
__global__ __launch_bounds__(256) void k_mlp3(const float* __restrict__ t2,
                                              const float* __restrict__ a2,
                                              const float* __restrict__ c2,
                                              const float* __restrict__ W3,
                                              const float* __restrict__ b3,
                                              float* __restrict__ prob) {
    int j = threadIdx.x & 63;
    int r = threadIdx.x >> 6;
    float aj = a2[j], cj = c2[j], wj = W3[j], bb = b3[0];
    for (int n = blockIdx.x * 4 + r; n < NN; n += 2048 * 4) {
        float h = fmaxf(t2[(size_t)n * 64 + j] * aj + cj, 0.f) * wj;
        #pragma unroll
        for (int off = 32; off > 0; off >>= 1) h += __shfl_xor(h, off, 64);
        if (j == 0) prob[n] = 1.f / (1.f + expf(-(h + bb)));
    }
}

extern "C" void kernel_launch(void* const* d_in, const int* in_sizes, int n_in,
                              void* d_out, int out_size, void* d_ws, size_t ws_size,
                              hipStream_t stream) {
    const float* init_emb = (const float*)d_in[0];
    const int* pe = (const int*)d_in[1];
    const int* ne = (const int*)d_in[2];
    const float* c1_Wp = (const float*)d_in[3];  const float* c1_bp = (const float*)d_in[4];
    const float* c1_Wn = (const float*)d_in[5];  const float* c1_bn = (const float*)d_in[6];
    const float* c1_Ws = (const float*)d_in[7];  const float* c1_bs = (const float*)d_in[8];
    const float* c2_Wp = (const float*)d_in[9];  const float* c2_bp = (const float*)d_in[10];
    const float* c2_Wn = (const float*)d_in[11]; const float* c2_bn = (const float*)d_in[12];
    const float* c2_Ws = (const float*)d_in[13]; const float* c2_bs = (const float*)d_in[14];
    const float* w_W = (const float*)d_in[15];   const float* w_b = (const float*)d_in[16];
    const float* m1_W = (const float*)d_in[17];  const float* m1_b = (const float*)d_in[18];
    const float* g1 = (const float*)d_in[19];    const float* b1 = (const float*)d_in[20];
    const float* m2_W = (const float*)d_in[21];  const float* m2_b = (const float*)d_in[22];
    const float* g2 = (const float*)d_in[23];    const float* b2 = (const float*)d_in[24];
    const float* m3_W = (const float*)d_in[25];  const float* m3_b = (const float*)d_in[26];

    // ---- workspace arena ----
    size_t off = 0;
    auto alloc = [&](size_t bytes) -> void* {
        void* r = (char*)d_ws + off;
        off += (bytes + 255) & ~(size_t)255;
        return r;
    };
    // zero region (front)
    int*   degP = (int*)alloc((size_t)NN * 4);
    int*   degN = (int*)alloc((size_t)NN * 4);
    int*   curP = (int*)alloc((size_t)NN * 4);
    int*   curN = (int*)alloc((size_t)NN * 4);
    float* sums = (float*)alloc(256 * 4);          // colsum1, colsq1, colsum2, colsq2
    size_t zero_bytes = off;
    // non-zeroed
    int*   rpP  = (int*)alloc((size_t)(NN + 1) * 4);
    int*   rpN  = (int*)alloc((size_t)(NN + 1) * 4);
    int*   csrP = (int*)alloc((size_t)EE * 4);
    int*   csrN = (int*)alloc((size_t)EE * 4);
    float* R1   = (float*)alloc((size_t)NN * 96 * 4);   // {xp,xn,xs} layer1 -> layer2 -> t1
    float* z1   = (float*)alloc((size_t)NN * 32 * 4);
    float* z2   = (float*)alloc((size_t)NN * 32 * 4);
    float* t2   = (float*)alloc((size_t)NN * 64 * 4);
    float* abc  = (float*)alloc(256 * 4);               // a1, c1, a2, c2

    float* xp = R1;
    float* xn = R1 + (size_t)NN * 32;
    float* xs = R1 + (size_t)NN * 64;
    float* t1 = R1;                                     // dead xp/xn region after wlin

    float* z_out = (float*)d_out;                       // [N,64]
    float* prob  = (float*)d_out + (size_t)NN * 64;     // [N,1]

    hipMemsetAsync(d_ws, 0, zero_bytes, stream);

    k_degree<<<(2 * EE + 255) / 256, 256, 0, stream>>>(pe, ne, degP, degN);
    k_scan<<<1, 1024, 0, stream>>>(degP, degN, rpP, rpN);
    k_scatter<<<(2 * EE + 255) / 256, 256, 0, stream>>>(pe, ne, rpP, rpN, curP, curN, csrP, csrN);

    // layer 1
    k_xf1<<<2048, 256, 0, stream>>>(init_emb, c1_Wp, c1_Wn, c1_Ws, xp, xn, xs);
    k_pull<<<2048, 256, 0, stream>>>(xp, xn, xs, rpP, csrP, rpN, csrN, c1_bp, c1_bn, c1_bs, z1);
    // layer 2
    k_xf2<<<2048, 256, 0, stream>>>(z1, c2_Wp, c2_Wn, c2_Ws, xp, xn, xs);
    k_pull<<<2048, 256, 0, stream>>>(xp, xn, xs, rpP, csrP, rpN, csrN, c2_bp, c2_bn, c2_bs, z2);
    // readout
    k_wlin_mlp1<<<2048, 256, 0, stream>>>(z2, w_W, w_b, m1_W, m1_b, z_out, t1, sums + 0, sums + 64);
    k_bnstats<<<1, 64, 0, stream>>>(sums + 0, sums + 64, g1, b1, abc + 0, abc + 64);
    k_mlp2<<<2048, 256, 0, stream>>>(t1, abc + 0, abc + 64, m2_W, m2_b, t2, sums + 128, sums + 192);
    k_bnstats<<<1, 64, 0, stream>>>(sums + 128, sums + 192, g2, b2, abc + 128, abc + 192);
    k_mlp3<<<2048, 256, 0, stream>>>(t2, abc + 128, abc + 192, m3_W, m3_b, prob);
}

// Round 5
// 592.998 us; speedup vs baseline: 1.8649x; 1.5063x over previous
//
#include <hip/hip_runtime.h>
#include <cstdint>
#include <cstddef>

#define NN 100000
#define EE 1000000
#define EPSF 1e-5f
#define SCAN_B 391  // ceil(100000/256)

__device__ __forceinline__ void fatomic(float* p, float v) { unsafeAtomicAdd(p, v); }

// ---- degree histogram (both relations), int atomics ----
__global__ __launch_bounds__(256) void k_degree(const int* __restrict__ pe,
                                                const int* __restrict__ ne,
                                                int* __restrict__ degP,
                                                int* __restrict__ degN) {
    int t = blockIdx.x * 256 + threadIdx.x;
    if (t < EE) {
        atomicAdd(&degP[pe[EE + t]], 1);
    } else if (t < 2 * EE) {
        int e = t - EE;
        atomicAdd(&degN[ne[EE + e]], 1);
    }
}

// ---- hierarchical scan, stage 1: block-local exclusive scan + block totals ----
__global__ __launch_bounds__(256) void k_scan1(const int* __restrict__ degP,
                                               const int* __restrict__ degN,
                                               int* __restrict__ rpP,
                                               int* __restrict__ rpN,
                                               int* __restrict__ partials) {
    int b = blockIdx.x;                 // 0..2*SCAN_B-1
    int rel = (b >= SCAN_B);
    int cb = rel ? b - SCAN_B : b;
    const int* deg = rel ? degN : degP;
    int* rp = rel ? rpN : rpP;
    int i = cb * 256 + threadIdx.x;
    int v = (i < NN) ? deg[i] : 0;
    __shared__ int s[256];
    s[threadIdx.x] = v;
    __syncthreads();
    for (int off = 1; off < 256; off <<= 1) {
        int u = (threadIdx.x >= off) ? s[threadIdx.x - off] : 0;
        __syncthreads();
        s[threadIdx.x] += u;
        __syncthreads();
    }
    if (i < NN) rp[i] = s[threadIdx.x] - v;       // local exclusive
    if (threadIdx.x == 255) partials[b] = s[255]; // block total
}

// ---- stage 2: scan the block totals (one small block), write grand totals ----
__global__ __launch_bounds__(512) void k_scan2(int* __restrict__ partials,
                                               int* __restrict__ rpP,
                                               int* __restrict__ rpN) {
    __shared__ int s[512];
    for (int rel = 0; rel < 2; rel++) {
        int* part = partials + rel * SCAN_B;
        int v = (threadIdx.x < SCAN_B) ? part[threadIdx.x] : 0;
        s[threadIdx.x] = v;
        __syncthreads();
        for (int off = 1; off < 512; off <<= 1) {
            int u = (threadIdx.x >= off) ? s[threadIdx.x - off] : 0;
            __syncthreads();
            s[threadIdx.x] += u;
            __syncthreads();
        }
        if (threadIdx.x < SCAN_B) part[threadIdx.x] = s[threadIdx.x] - v;  // exclusive
        if (threadIdx.x == 511) (rel ? rpN : rpP)[NN] = s[511];
        __syncthreads();
    }
}

// ---- stage 3: add block offsets ----
__global__ __launch_bounds__(256) void k_scan3(const int* __restrict__ partials,
                                               int* __restrict__ rpP,
                                               int* __restrict__ rpN) {
    int b = blockIdx.x;
    int rel = (b >= SCAN_B);
    int cb = rel ? b - SCAN_B : b;
    int* rp = rel ? rpN : rpP;
    int i = cb * 256 + threadIdx.x;
    if (i < NN) rp[i] += partials[b];
}

// ---- scatter edges into CSR (src lists grouped by dst) ----
__global__ __launch_bounds__(256) void k_scatter(const int* __restrict__ pe,
                                                 const int* __restrict__ ne,
                                                 const int* __restrict__ rpP,
                                                 const int* __restrict__ rpN,
                                                 int* __restrict__ curP,
                                                 int* __restrict__ curN,
                                                 int* __restrict__ csrP,
                                                 int* __restrict__ csrN) {
    int t = blockIdx.x * 256 + threadIdx.x;
    if (t < EE) {
        int dst = pe[EE + t];
        int slot = atomicAdd(&curP[dst], 1);
        csrP[rpP[dst] + slot] = pe[t];
    } else if (t < 2 * EE) {
        int e = t - EE;
        int dst = ne[EE + e];
        int slot = atomicAdd(&curN[dst], 1);
        csrN[rpN[dst] + slot] = ne[e];
    }
}

// ---- pre-transform 64->32 x3: xp=x@Wp, xn=x@Wn, xs=x@Ws ----
__global__ __launch_bounds__(256) void k_xf1(const float* __restrict__ x,
                                             const float* __restrict__ Wp,
                                             const float* __restrict__ Wn,
                                             const float* __restrict__ Ws,
                                             float* __restrict__ xp,
                                             float* __restrict__ xn,
                                             float* __restrict__ xs) {
    __shared__ float sWp[64 * 32], sWn[64 * 32], sWs[64 * 32];
    for (int i = threadIdx.x; i < 64 * 32; i += 256) { sWp[i] = Wp[i]; sWn[i] = Wn[i]; sWs[i] = Ws[i]; }
    __syncthreads();
    int lane = threadIdx.x & 63;
    int j = lane & 31;
    int half = lane >> 5;
    int wid = (blockIdx.x * 256 + threadIdx.x) >> 6;
    const int nw = (2048 * 256) >> 6;
    for (int p = wid; 2 * p < NN; p += nw) {
        int n = 2 * p + half;
        float vlo = x[(size_t)n * 64 + j];
        float vhi = x[(size_t)n * 64 + 32 + j];
        float ap = 0.f, an = 0.f, as = 0.f;
        #pragma unroll
        for (int k = 0; k < 64; k++) {
            float xv = (k < 32) ? __shfl(vlo, k, 32) : __shfl(vhi, k - 32, 32);
            ap += xv * sWp[k * 32 + j];
            an += xv * sWn[k * 32 + j];
            as += xv * sWs[k * 32 + j];
        }
        xp[(size_t)n * 32 + j] = ap;
        xn[(size_t)n * 32 + j] = an;
        xs[(size_t)n * 32 + j] = as;
    }
}

// ---- pre-transform 32->32 x3 ----
__global__ __launch_bounds__(256) void k_xf2(const float* __restrict__ z,
                                             const float* __restrict__ Wp,
                                             const float* __restrict__ Wn,
                                             const float* __restrict__ Ws,
                                             float* __restrict__ xp,
                                             float* __restrict__ xn,
                                             float* __restrict__ xs) {
    __shared__ float sWp[32 * 32], sWn[32 * 32], sWs[32 * 32];
    for (int i = threadIdx.x; i < 32 * 32; i += 256) { sWp[i] = Wp[i]; sWn[i] = Wn[i]; sWs[i] = Ws[i]; }
    __syncthreads();
    int lane = threadIdx.x & 63;
    int j = lane & 31;
    int half = lane >> 5;
    int wid = (blockIdx.x * 256 + threadIdx.x) >> 6;
    const int nw = (2048 * 256) >> 6;
    for (int p = wid; 2 * p < NN; p += nw) {
        int n = 2 * p + half;
        float v = z[(size_t)n * 32 + j];
        float ap = 0.f, an = 0.f, as = 0.f;
        #pragma unroll
        for (int k = 0; k < 32; k++) {
            float xv = __shfl(v, k, 32);
            ap += xv * sWp[k * 32 + j];
            an += xv * sWn[k * 32 + j];
            as += xv * sWs[k * 32 + j];
        }
        xp[(size_t)n * 32 + j] = ap;
        xn[(size_t)n * 32 + j] = an;
        xs[(size_t)n * 32 + j] = as;
    }
}

// ---- accumulate one relation's neighbors ----
__device__ __forceinline__ float pull_rel(const float* __restrict__ xsrc,
                                          const int* __restrict__ csr,
                                          int b0, int b1, int j, float acc) {
    for (int base = b0; base < b1; base += 32) {
        int rem = b1 - base;
        int cnt = min(rem, 32);
        int idx = (j < rem) ? csr[base + j] : 0;
        int i = 0;
        for (; i + 4 <= cnt; i += 4) {
            int s0 = __shfl(idx, i, 32);
            int s1 = __shfl(idx, i + 1, 32);
            int s2 = __shfl(idx, i + 2, 32);
            int s3 = __shfl(idx, i + 3, 32);
            float v0 = xsrc[(size_t)s0 * 32 + j];
            float v1 = xsrc[(size_t)s1 * 32 + j];
            float v2 = xsrc[(size_t)s2 * 32 + j];
            float v3 = xsrc[(size_t)s3 * 32 + j];
            acc += v0; acc += v1; acc += v2; acc += v3;
        }
        for (; i < cnt; i++) {
            int s = __shfl(idx, i, 32);
            acc += xsrc[(size_t)s * 32 + j];
        }
    }
    return acc;
}

// ---- pull aggregation + combine + tanh ----
__global__ __launch_bounds__(256) void k_pull(const float* __restrict__ xp,
                                              const float* __restrict__ xn,
                                              const float* __restrict__ xs,
                                              const int* __restrict__ rpP,
                                              const int* __restrict__ csrP,
                                              const int* __restrict__ rpN,
                                              const int* __restrict__ csrN,
                                              const float* __restrict__ bp,
                                              const float* __restrict__ bn,
                                              const float* __restrict__ bs,
                                              float* __restrict__ out) {
    int j = threadIdx.x & 31;
    int hw = (blockIdx.x * 256 + threadIdx.x) >> 5;
    const int nhw = (2048 * 256) >> 5;
    float bpj = bp[j], bnj = bn[j], bsj = bs[j];
    for (int n = hw; n < NN; n += nhw) {
        int p0 = rpP[n], p1 = rpP[n + 1];
        int n0 = rpN[n], n1 = rpN[n + 1];
        float acc = xs[(size_t)n * 32 + j] + bsj
                  + (float)(p1 - p0) * bpj + (float)(n1 - n0) * bnj;
        acc = pull_rel(xp, csrP, p0, p1, j, acc);
        acc = pull_rel(xn, csrN, n0, n1, j, acc);
        out[(size_t)n * 32 + j] = tanhf(acc);
    }
}

// ---- fused: z = tanh(z2 @ w_W + w_b)  (output 0), t1 = z @ m1_W + m1_b, BN stats ----
__global__ __launch_bounds__(256) void k_wlin_mlp1(const float* __restrict__ z2,
                                                   const float* __restrict__ Wl,
                                                   const float* __restrict__ bl,
                                                   const float* __restrict__ W1,
                                                   const float* __restrict__ b1_,
                                                   float* __restrict__ z,
                                                   float* __restrict__ t1,
                                                   float* __restrict__ colsum,
                                                   float* __restrict__ colsq) {
    int lane = threadIdx.x & 63;
    int wv = threadIdx.x >> 6;
    float wl[32];
    #pragma unroll
    for (int k = 0; k < 32; k++) wl[k] = Wl[k * 64 + lane];
    float w1[64];
    #pragma unroll
    for (int k = 0; k < 64; k++) w1[k] = W1[k * 64 + lane];
    float blj = bl[lane], b1j = b1_[lane];
    float lsum = 0.f, lsq = 0.f;
    for (int n = blockIdx.x * 4 + wv; n < NN; n += 2048 * 4) {
        float v = z2[(size_t)n * 32 + (lane & 31)];
        float s = blj;
        #pragma unroll
        for (int k = 0; k < 32; k++) s += __shfl(v, k, 64) * wl[k];
        float zv = tanhf(s);
        z[(size_t)n * 64 + lane] = zv;
        float t = b1j;
        #pragma unroll
        for (int k = 0; k < 64; k++) t += __shfl(zv, k, 64) * w1[k];
        t1[(size_t)n * 64 + lane] = t;
        lsum += t; lsq += t * t;
    }
    __shared__ float red[256], red2[256];
    red[threadIdx.x] = lsum; red2[threadIdx.x] = lsq;
    __syncthreads();
    if (threadIdx.x < 64) {
        float a = red[threadIdx.x] + red[threadIdx.x + 64] + red[threadIdx.x + 128] + red[threadIdx.x + 192];
        float q = red2[threadIdx.x] + red2[threadIdx.x + 64] + red2[threadIdx.x + 128] + red2[threadIdx.x + 192];
        fatomic(&colsum[threadIdx.x], a);
        fatomic(&colsq[threadIdx.x], q);
    }
}

// ---- BN stats -> affine coefficients a, c (h_norm = t*a + c) ----
__global__ void k_bnstats(const float* __restrict__ colsum, const float* __restrict__ colsq,
                          const float* __restrict__ g, const float* __restrict__ beta,
                          float* __restrict__ a, float* __restrict__ c) {
    int j = threadIdx.x;
    if (j < 64) {
        float m = colsum[j] * (1.f / NN);
        float v = colsq[j] * (1.f / NN) - m * m;
        float aj = g[j] * rsqrtf(v + EPSF);
        a[j] = aj;
        c[j] = beta[j] - m * aj;
    }
}

// ---- t2 = relu(t1*a1+c1) @ m2_W + m2_b, accumulate stats ----
__global__ __launch_bounds__(256) void k_mlp2(const float* __restrict__ t1,
                                              const float* __restrict__ a1,
                                              const float* __restrict__ c1,
                                              const float* __restrict__ W,
                                              const float* __restrict__ b,
                                              float* __restrict__ t2,
                                              float* __restrict__ colsum,
                                              float* __restrict__ colsq) {
    int lane = threadIdx.x & 63;
    int wv = threadIdx.x >> 6;
    float w[64];
    #pragma unroll
    for (int k = 0; k < 64; k++) w[k] = W[k * 64 + lane];
    float bj = b[lane];
    float sa = a1[lane], sc = c1[lane];
    float lsum = 0.f, lsq = 0.f;
    for (int n = blockIdx.x * 4 + wv; n < NN; n += 2048 * 4) {
        float v = t1[(size_t)n * 64 + lane];
        float h = fmaxf(v * sa + sc, 0.f);
        float s = bj;
        #pragma unroll
        for (int k = 0; k < 64; k++) s += __shfl(h, k, 64) * w[k];
        t2[(size_t)n * 64 + lane] = s;
        lsum += s; lsq += s * s;
    }
    __shared__ float red[256], red2[256];
    red[threadIdx.x] = lsum; red2[threadIdx.x] = lsq;
    __syncthreads();
    if (threadIdx.x < 64) {
        float a = red[threadIdx.x] + red[threadIdx.x + 64] + red[threadIdx.x + 128] + red[threadIdx.x + 192];
        float q = red2[threadIdx.x] + red2[threadIdx.x + 64] + red2[threadIdx.x + 128] + red2[threadIdx.x + 192];
        fatomic(&colsum[threadIdx.x], a);
        fatomic(&colsq[threadIdx.x], q);
    }
}

// ---- prob = sigmoid(relu(t2*a2+c2) @ m3_W + m3_b) ----
__global__ __launch_bounds__(256) void k_mlp3(const float* __restrict__ t2,
                                              const float* __restrict__ a2,
                                              const float* __restrict__ c2,
                                              const float* __restrict__ W3,
                                              const float* __restrict__ b3,
                                              float* __restrict__ prob) {
    int j = threadIdx.x & 63;
    int r = threadIdx.x >> 6;
    float aj = a2[j], cj = c2[j], wj = W3[j], bb = b3[0];
    for (int n = blockIdx.x * 4 + r; n < NN; n += 2048 * 4) {
        float h = fmaxf(t2[(size_t)n * 64 + j] * aj + cj, 0.f) * wj;
        #pragma unroll
        for (int off = 32; off > 0; off >>= 1) h += __shfl_xor(h, off, 64);
        if (j == 0) prob[n] = 1.f / (1.f + expf(-(h + bb)));
    }
}

extern "C" void kernel_launch(void* const* d_in, const int* in_sizes, int n_in,
                              void* d_out, int out_size, void* d_ws, size_t ws_size,
                              hipStream_t stream) {
    const float* init_emb = (const float*)d_in[0];
    const int* pe = (const int*)d_in[1];
    const int* ne = (const int*)d_in[2];
    const float* c1_Wp = (const float*)d_in[3];  const float* c1_bp = (const float*)d_in[4];
    const float* c1_Wn = (const float*)d_in[5];  const float* c1_bn = (const float*)d_in[6];
    const float* c1_Ws = (const float*)d_in[7];  const float* c1_bs = (const float*)d_in[8];
    const float* c2_Wp = (const float*)d_in[9];  const float* c2_bp = (const float*)d_in[10];
    const float* c2_Wn = (const float*)d_in[11]; const float* c2_bn = (const float*)d_in[12];
    const float* c2_Ws = (const float*)d_in[13]; const float* c2_bs = (const float*)d_in[14];
    const float* w_W = (const float*)d_in[15];   const float* w_b = (const float*)d_in[16];
    const float* m1_W = (const float*)d_in[17];  const float* m1_b = (const float*)d_in[18];
    const float* g1 = (const float*)d_in[19];    const float* b1 = (const float*)d_in[20];
    const float* m2_W = (const float*)d_in[21];  const float* m2_b = (const float*)d_in[22];
    const float* g2 = (const float*)d_in[23];    const float* b2 = (const float*)d_in[24];
    const float* m3_W = (const float*)d_in[25];  const float* m3_b = (const float*)d_in[26];

    // ---- workspace arena ----
    size_t off = 0;
    auto alloc = [&](size_t bytes) -> void* {
        void* r = (char*)d_ws + off;
        off += (bytes + 255) & ~(size_t)255;
        return r;
    };
    // zero region (front)
    int*   degP = (int*)alloc((size_t)NN * 4);
    int*   degN = (int*)alloc((size_t)NN * 4);
    int*   curP = (int*)alloc((size_t)NN * 4);
    int*   curN = (int*)alloc((size_t)NN * 4);
    float* sums = (float*)alloc(256 * 4);          // colsum1, colsq1, colsum2, colsq2
    size_t zero_bytes = off;
    // non-zeroed
    int*   rpP  = (int*)alloc((size_t)(NN + 1) * 4);
    int*   rpN  = (int*)alloc((size_t)(NN + 1) * 4);
    int*   part = (int*)alloc((size_t)(2 * SCAN_B) * 4);
    int*   csrP = (int*)alloc((size_t)EE * 4);
    int*   csrN = (int*)alloc((size_t)EE * 4);
    float* R1   = (float*)alloc((size_t)NN * 96 * 4);   // {xp,xn,xs} layer1 -> layer2 -> t1
    float* z1   = (float*)alloc((size_t)NN * 32 * 4);
    float* z2   = (float*)alloc((size_t)NN * 32 * 4);
    float* t2   = (float*)alloc((size_t)NN * 64 * 4);
    float* abc  = (float*)alloc(256 * 4);               // a1, c1, a2, c2

    float* xp = R1;
    float* xn = R1 + (size_t)NN * 32;
    float* xs = R1 + (size_t)NN * 64;
    float* t1 = R1;                                     // dead xp/xn region after wlin

    float* z_out = (float*)d_out;                       // [N,64]
    float* prob  = (float*)d_out + (size_t)NN * 64;     // [N,1]

    hipMemsetAsync(d_ws, 0, zero_bytes, stream);

    k_degree<<<(2 * EE + 255) / 256, 256, 0, stream>>>(pe, ne, degP, degN);
    k_scan1<<<2 * SCAN_B, 256, 0, stream>>>(degP, degN, rpP, rpN, part);
    k_scan2<<<1, 512, 0, stream>>>(part, rpP, rpN);
    k_scan3<<<2 * SCAN_B, 256, 0, stream>>>(part, rpP, rpN);
    k_scatter<<<(2 * EE + 255) / 256, 256, 0, stream>>>(pe, ne, rpP, rpN, curP, curN, csrP, csrN);

    // layer 1
    k_xf1<<<2048, 256, 0, stream>>>(init_emb, c1_Wp, c1_Wn, c1_Ws, xp, xn, xs);
    k_pull<<<2048, 256, 0, stream>>>(xp, xn, xs, rpP, csrP, rpN, csrN, c1_bp, c1_bn, c1_bs, z1);
    // layer 2
    k_xf2<<<2048, 256, 0, stream>>>(z1, c2_Wp, c2_Wn, c2_Ws, xp, xn, xs);
    k_pull<<<2048, 256, 0, stream>>>(xp, xn, xs, rpP, csrP, rpN, csrN, c2_bp, c2_bn, c2_bs, z2);
    // readout
    k_wlin_mlp1<<<2048, 256, 0, stream>>>(z2, w_W, w_b, m1_W, m1_b, z_out, t1, sums + 0, sums + 64);
    k_bnstats<<<1, 64, 0, stream>>>(sums + 0, sums + 64, g1, b1, abc + 0, abc + 64);
    k_mlp2<<<2048, 256, 0, stream>>>(t1, abc + 0, abc + 64, m2_W, m2_b, t2, sums + 128, sums + 192);
    k_bnstats<<<1, 64, 0, stream>>>(sums + 128, sums + 192, g2, b2, abc + 128, abc + 192);
    k_mlp3<<<2048, 256, 0, stream>>>(t2, abc + 128, abc + 192, m3_W, m3_b, prob);
}

// Round 6
// 439.685 us; speedup vs baseline: 2.5151x; 1.3487x over previous
//
#include <hip/hip_runtime.h>
#include <cstdint>
#include <cstddef>

#define NN 100000
#define EE 1000000
#define EPSF 1e-5f
#define NBUK 391          // node buckets per relation: ceil(100000/256), dst>>8
#define NBUK2 (2*NBUK)    // both relations
#define NBLK 256          // edge-chunk blocks for hist/binscatter
#define EPB 7813          // ceil(2*EE / NBLK)
#define GSB 782           // scan blocks over NBUK2*NBLK entries (=200192/256)

__device__ __forceinline__ void fatomic(float* p, float v) { unsafeAtomicAdd(p, v); }

// edge slot s in [0,2EE): rel 0 = pos, rel 1 = neg
__device__ __forceinline__ void edge_of(const int* __restrict__ pe, const int* __restrict__ ne,
                                        int s, int& src, int& dst, int& bucket) {
    if (s < EE) { src = pe[s]; dst = pe[EE + s]; bucket = dst >> 8; }
    else        { src = ne[s - EE]; dst = ne[s]; bucket = NBUK + (dst >> 8); }
}

// ---- pass 1: per-block bucket histogram ----
__global__ __launch_bounds__(256) void k_hist(const int* __restrict__ pe,
                                              const int* __restrict__ ne,
                                              int* __restrict__ hist) {
    __shared__ int lh[NBUK2];
    for (int i = threadIdx.x; i < NBUK2; i += 256) lh[i] = 0;
    __syncthreads();
    int start = blockIdx.x * EPB, end = min(start + EPB, 2 * EE);
    for (int s = start + threadIdx.x; s < end; s += 256) {
        int src, dst, bucket;
        edge_of(pe, ne, s, src, dst, bucket);
        atomicAdd(&lh[bucket], 1);
    }
    __syncthreads();
    for (int i = threadIdx.x; i < NBUK2; i += 256)
        hist[i * NBLK + blockIdx.x] = lh[i];   // bucket-major
}

// ---- generic hierarchical exclusive scan over NBUK2*NBLK ints ----
__global__ __launch_bounds__(256) void k_gscan1(const int* __restrict__ in,
                                                int* __restrict__ out,
                                                int* __restrict__ partials) {
    int i = blockIdx.x * 256 + threadIdx.x;
    int v = in[i];
    __shared__ int s[256];
    s[threadIdx.x] = v;
    __syncthreads();
    for (int off = 1; off < 256; off <<= 1) {
        int u = (threadIdx.x >= off) ? s[threadIdx.x - off] : 0;
        __syncthreads();
        s[threadIdx.x] += u;
        __syncthreads();
    }
    out[i] = s[threadIdx.x] - v;
    if (threadIdx.x == 255) partials[blockIdx.x] = s[255];
}

__global__ __launch_bounds__(1024) void k_gscan2(int* __restrict__ partials) {
    __shared__ int s[1024];
    int v = (threadIdx.x < GSB) ? partials[threadIdx.x] : 0;
    s[threadIdx.x] = v;
    __syncthreads();
    for (int off = 1; off < 1024; off <<= 1) {
        int u = (threadIdx.x >= off) ? s[threadIdx.x - off] : 0;
        __syncthreads();
        s[threadIdx.x] += u;
        __syncthreads();
    }
    if (threadIdx.x < GSB) partials[threadIdx.x] = s[threadIdx.x] - v;
}

__global__ __launch_bounds__(256) void k_gscan3(const int* __restrict__ partials,
                                                int* __restrict__ out) {
    out[blockIdx.x * 256 + threadIdx.x] += partials[blockIdx.x];
}

// ---- pass 2: scatter edges into bucket-grouped staging (block-exclusive runs) ----
__global__ __launch_bounds__(256) void k_binscatter(const int* __restrict__ pe,
                                                    const int* __restrict__ ne,
                                                    const int* __restrict__ soff,
                                                    unsigned long long* __restrict__ staging) {
    __shared__ int cur[NBUK2];
    for (int i = threadIdx.x; i < NBUK2; i += 256)
        cur[i] = soff[i * NBLK + blockIdx.x];
    __syncthreads();
    int start = blockIdx.x * EPB, end = min(start + EPB, 2 * EE);
    for (int s = start + threadIdx.x; s < end; s += 256) {
        int src, dst, bucket;
        edge_of(pe, ne, s, src, dst, bucket);
        int pos = atomicAdd(&cur[bucket], 1);
        staging[pos] = ((unsigned long long)(unsigned)dst << 32) | (unsigned)src;
    }
}

// ---- pass 3: per-bucket local build: rp (degree+scan in LDS) + csr scatter ----
__global__ __launch_bounds__(256) void k_local(const unsigned long long* __restrict__ staging,
                                               const int* __restrict__ soff,
                                               int* __restrict__ rpP,
                                               int* __restrict__ rpN,
                                               int* __restrict__ csrAll) {
    int bucket = blockIdx.x;
    int rel = bucket >= NBUK;
    int nodeBase = (bucket - rel * NBUK) << 8;
    int bstart = soff[bucket * NBLK];
    int bend = (bucket == NBUK2 - 1) ? 2 * EE : soff[(bucket + 1) * NBLK];
    int tid = threadIdx.x;
    __shared__ int deg[256], sc[256];
    deg[tid] = 0;
    __syncthreads();
    for (int i = bstart + tid; i < bend; i += 256) {
        int d = (int)(staging[i] >> 32) & 255;
        atomicAdd(&deg[d], 1);
    }
    __syncthreads();
    int dv = deg[tid];
    sc[tid] = dv;
    __syncthreads();
    for (int off = 1; off < 256; off <<= 1) {
        int u = (tid >= off) ? sc[tid - off] : 0;
        __syncthreads();
        sc[tid] += u;
        __syncthreads();
    }
    int lrp = sc[tid] - dv;  // bucket-local exclusive prefix
    int nCount = min(256, NN - nodeBase);
    int relbase = rel ? EE : 0;
    if (tid < nCount) (rel ? rpN : rpP)[nodeBase + tid] = bstart - relbase + lrp;
    if (bucket == NBUK - 1 && tid == 0) rpP[NN] = EE;
    if (bucket == NBUK2 - 1 && tid == 0) rpN[NN] = EE;
    deg[tid] = lrp;          // reuse as cursor
    __syncthreads();
    for (int i = bstart + tid; i < bend; i += 256) {
        unsigned long long v = staging[i];
        int d = (int)(v >> 32) & 255;
        int src = (int)(v & 0xffffffffu);
        int slot = atomicAdd(&deg[d], 1);
        csrAll[bstart + slot] = src;
    }
}

// ---- pre-transform 64->32 x3: xp=x@Wp, xn=x@Wn, xs=x@Ws ----
__global__ __launch_bounds__(256) void k_xf1(const float* __restrict__ x,
                                             const float* __restrict__ Wp,
                                             const float* __restrict__ Wn,
                                             const float* __restrict__ Ws,
                                             float* __restrict__ xp,
                                             float* __restrict__ xn,
                                             float* __restrict__ xs) {
    __shared__ float sWp[64 * 32], sWn[64 * 32], sWs[64 * 32];
    for (int i = threadIdx.x; i < 64 * 32; i += 256) { sWp[i] = Wp[i]; sWn[i] = Wn[i]; sWs[i] = Ws[i]; }
    __syncthreads();
    int lane = threadIdx.x & 63;
    int j = lane & 31;
    int half = lane >> 5;
    int wid = (blockIdx.x * 256 + threadIdx.x) >> 6;
    const int nw = (2048 * 256) >> 6;
    for (int p = wid; 2 * p < NN; p += nw) {
        int n = 2 * p + half;
        float vlo = x[(size_t)n * 64 + j];
        float vhi = x[(size_t)n * 64 + 32 + j];
        float ap = 0.f, an = 0.f, as = 0.f;
        #pragma unroll
        for (int k = 0; k < 64; k++) {
            float xv = (k < 32) ? __shfl(vlo, k, 32) : __shfl(vhi, k - 32, 32);
            ap += xv * sWp[k * 32 + j];
            an += xv * sWn[k * 32 + j];
            as += xv * sWs[k * 32 + j];
        }
        xp[(size_t)n * 32 + j] = ap;
        xn[(size_t)n * 32 + j] = an;
        xs[(size_t)n * 32 + j] = as;
    }
}

// ---- pre-transform 32->32 x3 ----
__global__ __launch_bounds__(256) void k_xf2(const float* __restrict__ z,
                                             const float* __restrict__ Wp,
                                             const float* __restrict__ Wn,
                                             const float* __restrict__ Ws,
                                             float* __restrict__ xp,
                                             float* __restrict__ xn,
                                             float* __restrict__ xs) {
    __shared__ float sWp[32 * 32], sWn[32 * 32], sWs[32 * 32];
    for (int i = threadIdx.x; i < 32 * 32; i += 256) { sWp[i] = Wp[i]; sWn[i] = Wn[i]; sWs[i] = Ws[i]; }
    __syncthreads();
    int lane = threadIdx.x & 63;
    int j = lane & 31;
    int half = lane >> 5;
    int wid = (blockIdx.x * 256 + threadIdx.x) >> 6;
    const int nw = (2048 * 256) >> 6;
    for (int p = wid; 2 * p < NN; p += nw) {
        int n = 2 * p + half;
        float v = z[(size_t)n * 32 + j];
        float ap = 0.f, an = 0.f, as = 0.f;
        #pragma unroll
        for (int k = 0; k < 32; k++) {
            float xv = __shfl(v, k, 32);
            ap += xv * sWp[k * 32 + j];
            an += xv * sWn[k * 32 + j];
            as += xv * sWs[k * 32 + j];
        }
        xp[(size_t)n * 32 + j] = ap;
        xn[(size_t)n * 32 + j] = an;
        xs[(size_t)n * 32 + j] = as;
    }
}

// ---- accumulate one relation's neighbors ----
__device__ __forceinline__ float pull_rel(const float* __restrict__ xsrc,
                                          const int* __restrict__ csr,
                                          int b0, int b1, int j, float acc) {
    for (int base = b0; base < b1; base += 32) {
        int rem = b1 - base;
        int cnt = min(rem, 32);
        int idx = (j < rem) ? csr[base + j] : 0;
        int i = 0;
        for (; i + 4 <= cnt; i += 4) {
            int s0 = __shfl(idx, i, 32);
            int s1 = __shfl(idx, i + 1, 32);
            int s2 = __shfl(idx, i + 2, 32);
            int s3 = __shfl(idx, i + 3, 32);
            float v0 = xsrc[(size_t)s0 * 32 + j];
            float v1 = xsrc[(size_t)s1 * 32 + j];
            float v2 = xsrc[(size_t)s2 * 32 + j];
            float v3 = xsrc[(size_t)s3 * 32 + j];
            acc += v0; acc += v1; acc += v2; acc += v3;
        }
        for (; i < cnt; i++) {
            int s = __shfl(idx, i, 32);
            acc += xsrc[(size_t)s * 32 + j];
        }
    }
    return acc;
}

// ---- pull aggregation + combine + tanh ----
__global__ __launch_bounds__(256) void k_pull(const float* __restrict__ xp,
                                              const float* __restrict__ xn,
                                              const float* __restrict__ xs,
                                              const int* __restrict__ rpP,
                                              const int* __restrict__ csrP,
                                              const int* __restrict__ rpN,
                                              const int* __restrict__ csrN,
                                              const float* __restrict__ bp,
                                              const float* __restrict__ bn,
                                              const float* __restrict__ bs,
                                              float* __restrict__ out) {
    int j = threadIdx.x & 31;
    int hw = (blockIdx.x * 256 + threadIdx.x) >> 5;
    const int nhw = (2048 * 256) >> 5;
    float bpj = bp[j], bnj = bn[j], bsj = bs[j];
    for (int n = hw; n < NN; n += nhw) {
        int p0 = rpP[n], p1 = rpP[n + 1];
        int n0 = rpN[n], n1 = rpN[n + 1];
        float acc = xs[(size_t)n * 32 + j] + bsj
                  + (float)(p1 - p0) * bpj + (float)(n1 - n0) * bnj;
        acc = pull_rel(xp, csrP, p0, p1, j, acc);
        acc = pull_rel(xn, csrN, n0, n1, j, acc);
        out[(size_t)n * 32 + j] = tanhf(acc);
    }
}

// ---- fused: z = tanh(z2 @ w_W + w_b)  (output 0), t1 = z @ m1_W + m1_b, BN stats ----
__global__ __launch_bounds__(256) void k_wlin_mlp1(const float* __restrict__ z2,
                                                   const float* __restrict__ Wl,
                                                   const float* __restrict__ bl,
                                                   const float* __restrict__ W1,
                                                   const float* __restrict__ b1_,
                                                   float* __restrict__ z,
                                                   float* __restrict__ t1,
                                                   float* __restrict__ colsum,
                                                   float* __restrict__ colsq) {
    int lane = threadIdx.x & 63;
    int wv = threadIdx.x >> 6;
    float wl[32];
    #pragma unroll
    for (int k = 0; k < 32; k++) wl[k] = Wl[k * 64 + lane];
    float w1[64];
    #pragma unroll
    for (int k = 0; k < 64; k++) w1[k] = W1[k * 64 + lane];
    float blj = bl[lane], b1j = b1_[lane];
    float lsum = 0.f, lsq = 0.f;
    for (int n = blockIdx.x * 4 + wv; n < NN; n += 2048 * 4) {
        float v = z2[(size_t)n * 32 + (lane & 31)];
        float s = blj;
        #pragma unroll
        for (int k = 0; k < 32; k++) s += __shfl(v, k, 64) * wl[k];
        float zv = tanhf(s);
        z[(size_t)n * 64 + lane] = zv;
        float t = b1j;
        #pragma unroll
        for (int k = 0; k < 64; k++) t += __shfl(zv, k, 64) * w1[k];
        t1[(size_t)n * 64 + lane] = t;
        lsum += t; lsq += t * t;
    }
    __shared__ float red[256], red2[256];
    red[threadIdx.x] = lsum; red2[threadIdx.x] = lsq;
    __syncthreads();
    if (threadIdx.x < 64) {
        float a = red[threadIdx.x] + red[threadIdx.x + 64] + red[threadIdx.x + 128] + red[threadIdx.x + 192];
        float q = red2[threadIdx.x] + red2[threadIdx.x + 64] + red2[threadIdx.x + 128] + red2[threadIdx.x + 192];
        fatomic(&colsum[threadIdx.x], a);
        fatomic(&colsq[threadIdx.x], q);
    }
}

// ---- BN stats -> affine coefficients a, c (h_norm = t*a + c) ----
__global__ void k_bnstats(const float* __restrict__ colsum, const float* __restrict__ colsq,
                          const float* __restrict__ g, const float* __restrict__ beta,
                          float* __restrict__ a, float* __restrict__ c) {
    int j = threadIdx.x;
    if (j < 64) {
        float m = colsum[j] * (1.f / NN);
        float v = colsq[j] * (1.f / NN) - m * m;
        float aj = g[j] * rsqrtf(v + EPSF);
        a[j] = aj;
        c[j] = beta[j] - m * aj;
    }
}

// ---- t2 = relu(t1*a1+c1) @ m2_W + m2_b, accumulate stats ----
__global__ __launch_bounds__(256) void k_mlp2(const float* __restrict__ t1,
                                              const float* __restrict__ a1,
                                              const float* __restrict__ c1,
                                              const float* __restrict__ W,
                                              const float* __restrict__ b,
                                              float* __restrict__ t2,
                                              float* __restrict__ colsum,
                                              float* __restrict__ colsq) {
    int lane = threadIdx.x & 63;
    int wv = threadIdx.x >> 6;
    float w[64];
    #pragma unroll
    for (int k = 0; k < 64; k++) w[k] = W[k * 64 + lane];
    float bj = b[lane];
    float sa = a1[lane], sc = c1[lane];
    float lsum = 0.f, lsq = 0.f;
    for (int n = blockIdx.x * 4 + wv; n < NN; n += 2048 * 4) {
        float v = t1[(size_t)n * 64 + lane];
        float h = fmaxf(v * sa + sc, 0.f);
        float s = bj;
        #pragma unroll
        for (int k = 0; k < 64; k++) s += __shfl(h, k, 64) * w[k];
        t2[(size_t)n * 64 + lane] = s;
        lsum += s; lsq += s * s;
    }
    __shared__ float red[256], red2[256];
    red[threadIdx.x] = lsum; red2[threadIdx.x] = lsq;
    __syncthreads();
    if (threadIdx.x < 64) {
        float a = red[threadIdx.x] + red[threadIdx.x + 64] + red[threadIdx.x + 128] + red[threadIdx.x + 192];
        float q = red2[threadIdx.x] + red2[threadIdx.x + 64] + red2[threadIdx.x + 128] + red2[threadIdx.x + 192];
        fatomic(&colsum[threadIdx.x], a);
        fatomic(&colsq[threadIdx.x], q);
    }
}

// ---- prob = sigmoid(relu(t2*a2+c2) @ m3_W + m3_b) ----
__global__ __launch_bounds__(256) void k_mlp3(const float* __restrict__ t2,
                                              const float* __restrict__ a2,
                                              const float* __restrict__ c2,
                                              const float* __restrict__ W3,
                                              const float* __restrict__ b3,
                                              float* __restrict__ prob) {
    int j = threadIdx.x & 63;
    int r = threadIdx.x >> 6;
    float aj = a2[j], cj = c2[j], wj = W3[j], bb = b3[0];
    for (int n = blockIdx.x * 4 + r; n < NN; n += 2048 * 4) {
        float h = fmaxf(t2[(size_t)n * 64 + j] * aj + cj, 0.f) * wj;
        #pragma unroll
        for (int off = 32; off > 0; off >>= 1) h += __shfl_xor(h, off, 64);
        if (j == 0) prob[n] = 1.f / (1.f + expf(-(h + bb)));
    }
}

extern "C" void kernel_launch(void* const* d_in, const int* in_sizes, int n_in,
                              void* d_out, int out_size, void* d_ws, size_t ws_size,
                              hipStream_t stream) {
    const float* init_emb = (const float*)d_in[0];
    const int* pe = (const int*)d_in[1];
    const int* ne = (const int*)d_in[2];
    const float* c1_Wp = (const float*)d_in[3];  const float* c1_bp = (const float*)d_in[4];
    const float* c1_Wn = (const float*)d_in[5];  const float* c1_bn = (const float*)d_in[6];
    const float* c1_Ws = (const float*)d_in[7];  const float* c1_bs = (const float*)d_in[8];
    const float* c2_Wp = (const float*)d_in[9];  const float* c2_bp = (const float*)d_in[10];
    const float* c2_Wn = (const float*)d_in[11]; const float* c2_bn = (const float*)d_in[12];
    const float* c2_Ws = (const float*)d_in[13]; const float* c2_bs = (const float*)d_in[14];
    const float* w_W = (const float*)d_in[15];   const float* w_b = (const float*)d_in[16];
    const float* m1_W = (const float*)d_in[17];  const float* m1_b = (const float*)d_in[18];
    const float* g1 = (const float*)d_in[19];    const float* b1 = (const float*)d_in[20];
    const float* m2_W = (const float*)d_in[21];  const float* m2_b = (const float*)d_in[22];
    const float* g2 = (const float*)d_in[23];    const float* b2 = (const float*)d_in[24];
    const float* m3_W = (const float*)d_in[25];  const float* m3_b = (const float*)d_in[26];

    // ---- workspace arena ----
    size_t off = 0;
    auto alloc = [&](size_t bytes) -> void* {
        void* r = (char*)d_ws + off;
        off += (bytes + 255) & ~(size_t)255;
        return r;
    };
    // zero region (front): only BN stat accumulators
    float* sums = (float*)alloc(256 * 4);               // colsum1, colsq1, colsum2, colsq2
    size_t zero_bytes = off;
    // CSR-build region (dead after second k_pull; t2 aliases it later)
    size_t csr_region = off;
    int*   hist = (int*)alloc((size_t)NBUK2 * NBLK * 4);        // 800KB
    int*   soff = (int*)alloc((size_t)NBUK2 * NBLK * 4);        // 800KB
    int*   part = (int*)alloc((size_t)1024 * 4);
    unsigned long long* staging = (unsigned long long*)alloc((size_t)2 * EE * 8);  // 16MB
    int*   csrAll = (int*)alloc((size_t)2 * EE * 4);            // 8MB
    // persistent
    int*   rpP  = (int*)alloc((size_t)(NN + 1) * 4);
    int*   rpN  = (int*)alloc((size_t)(NN + 1) * 4);
    float* R1   = (float*)alloc((size_t)NN * 96 * 4);   // {xp,xn,xs} layer1 -> layer2 -> t1
    float* z1   = (float*)alloc((size_t)NN * 32 * 4);
    float* z2   = (float*)alloc((size_t)NN * 32 * 4);
    float* abc  = (float*)alloc(256 * 4);               // a1, c1, a2, c2

    int* csrP = csrAll;
    int* csrN = csrAll + (size_t)EE;
    float* xp = R1;
    float* xn = R1 + (size_t)NN * 32;
    float* xs = R1 + (size_t)NN * 64;
    float* t1 = R1;                                     // dead xp/xn region after wlin
    float* t2 = (float*)((char*)d_ws + csr_region);     // aliases CSR-build scratch (25.6MB fits)

    float* z_out = (float*)d_out;                       // [N,64]
    float* prob  = (float*)d_out + (size_t)NN * 64;     // [N,1]

    hipMemsetAsync(d_ws, 0, zero_bytes, stream);

    // ---- CSR build: hist -> scan -> bin scatter -> per-bucket local build ----
    k_hist<<<NBLK, 256, 0, stream>>>(pe, ne, hist);
    k_gscan1<<<GSB, 256, 0, stream>>>(hist, soff, part);
    k_gscan2<<<1, 1024, 0, stream>>>(part);
    k_gscan3<<<GSB, 256, 0, stream>>>(part, soff);
    k_binscatter<<<NBLK, 256, 0, stream>>>(pe, ne, soff, staging);
    k_local<<<NBUK2, 256, 0, stream>>>(staging, soff, rpP, rpN, csrAll);

    // layer 1
    k_xf1<<<2048, 256, 0, stream>>>(init_emb, c1_Wp, c1_Wn, c1_Ws, xp, xn, xs);
    k_pull<<<2048, 256, 0, stream>>>(xp, xn, xs, rpP, csrP, rpN, csrN, c1_bp, c1_bn, c1_bs, z1);
    // layer 2
    k_xf2<<<2048, 256, 0, stream>>>(z1, c2_Wp, c2_Wn, c2_Ws, xp, xn, xs);
    k_pull<<<2048, 256, 0, stream>>>(xp, xn, xs, rpP, csrP, rpN, csrN, c2_bp, c2_bn, c2_bs, z2);
    // readout
    k_wlin_mlp1<<<2048, 256, 0, stream>>>(z2, w_W, w_b, m1_W, m1_b, z_out, t1, sums + 0, sums + 64);
    k_bnstats<<<1, 64, 0, stream>>>(sums + 0, sums + 64, g1, b1, abc + 0, abc + 64);
    k_mlp2<<<2048, 256, 0, stream>>>(t1, abc + 0, abc + 64, m2_W, m2_b, t2, sums + 128, sums + 192);
    k_bnstats<<<1, 64, 0, stream>>>(sums + 128, sums + 192, g2, b2, abc + 128, abc + 192);
    k_mlp3<<<2048, 256, 0, stream>>>(t2, abc + 128, abc + 192, m3_W, m3_b, prob);
}

// Round 7
// 379.835 us; speedup vs baseline: 2.9115x; 1.1576x over previous
//
#include <hip/hip_runtime.h>
#include <cstdint>
#include <cstddef>

#define NN 100000
#define EE 1000000
#define EPSF 1e-5f
#define NBUK 391          // node buckets per relation: ceil(100000/256), dst>>8
#define NBUK2 (2*NBUK)    // both relations
#define NBLK 256          // edge-chunk blocks for hist/binscatter
#define EPB 7813          // ceil(2*EE / NBLK)
#define GSB 782           // scan blocks over NBUK2*NBLK entries (=200192/256)
#define GTILES ((NN + 63) / 64)   // 1563 64-node GEMM tiles

__device__ __forceinline__ void fatomic(float* p, float v) { unsafeAtomicAdd(p, v); }

// edge slot s in [0,2EE): rel 0 = pos, rel 1 = neg
__device__ __forceinline__ void edge_of(const int* __restrict__ pe, const int* __restrict__ ne,
                                        int s, int& src, int& dst, int& bucket) {
    if (s < EE) { src = pe[s]; dst = pe[EE + s]; bucket = dst >> 8; }
    else        { src = ne[s - EE]; dst = ne[s]; bucket = NBUK + (dst >> 8); }
}

// ---- pass 1: per-block bucket histogram ----
__global__ __launch_bounds__(256) void k_hist(const int* __restrict__ pe,
                                              const int* __restrict__ ne,
                                              int* __restrict__ hist) {
    __shared__ int lh[NBUK2];
    for (int i = threadIdx.x; i < NBUK2; i += 256) lh[i] = 0;
    __syncthreads();
    int start = blockIdx.x * EPB, end = min(start + EPB, 2 * EE);
    for (int s = start + threadIdx.x; s < end; s += 256) {
        int src, dst, bucket;
        edge_of(pe, ne, s, src, dst, bucket);
        atomicAdd(&lh[bucket], 1);
    }
    __syncthreads();
    for (int i = threadIdx.x; i < NBUK2; i += 256)
        hist[i * NBLK + blockIdx.x] = lh[i];   // bucket-major
}

// ---- generic hierarchical exclusive scan over NBUK2*NBLK ints ----
__global__ __launch_bounds__(256) void k_gscan1(const int* __restrict__ in,
                                                int* __restrict__ out,
                                                int* __restrict__ partials) {
    int i = blockIdx.x * 256 + threadIdx.x;
    int v = in[i];
    __shared__ int s[256];
    s[threadIdx.x] = v;
    __syncthreads();
    for (int off = 1; off < 256; off <<= 1) {
        int u = (threadIdx.x >= off) ? s[threadIdx.x - off] : 0;
        __syncthreads();
        s[threadIdx.x] += u;
        __syncthreads();
    }
    out[i] = s[threadIdx.x] - v;
    if (threadIdx.x == 255) partials[blockIdx.x] = s[255];
}

__global__ __launch_bounds__(1024) void k_gscan2(int* __restrict__ partials) {
    __shared__ int s[1024];
    int v = (threadIdx.x < GSB) ? partials[threadIdx.x] : 0;
    s[threadIdx.x] = v;
    __syncthreads();
    for (int off = 1; off < 1024; off <<= 1) {
        int u = (threadIdx.x >= off) ? s[threadIdx.x - off] : 0;
        __syncthreads();
        s[threadIdx.x] += u;
        __syncthreads();
    }
    if (threadIdx.x < GSB) partials[threadIdx.x] = s[threadIdx.x] - v;
}

__global__ __launch_bounds__(256) void k_gscan3(const int* __restrict__ partials,
                                                int* __restrict__ out) {
    out[blockIdx.x * 256 + threadIdx.x] += partials[blockIdx.x];
}

// ---- pass 2: scatter edges into bucket-grouped staging (block-exclusive runs) ----
__global__ __launch_bounds__(256) void k_binscatter(const int* __restrict__ pe,
                                                    const int* __restrict__ ne,
                                                    const int* __restrict__ soff,
                                                    unsigned long long* __restrict__ staging) {
    __shared__ int cur[NBUK2];
    for (int i = threadIdx.x; i < NBUK2; i += 256)
        cur[i] = soff[i * NBLK + blockIdx.x];
    __syncthreads();
    int start = blockIdx.x * EPB, end = min(start + EPB, 2 * EE);
    for (int s = start + threadIdx.x; s < end; s += 256) {
        int src, dst, bucket;
        edge_of(pe, ne, s, src, dst, bucket);
        int pos = atomicAdd(&cur[bucket], 1);
        staging[pos] = ((unsigned long long)(unsigned)dst << 32) | (unsigned)src;
    }
}

// ---- pass 3: per-bucket local build: rp (degree+scan in LDS) + csr scatter ----
__global__ __launch_bounds__(256) void k_local(const unsigned long long* __restrict__ staging,
                                               const int* __restrict__ soff,
                                               int* __restrict__ rpP,
                                               int* __restrict__ rpN,
                                               int* __restrict__ csrAll) {
    int bucket = blockIdx.x;
    int rel = bucket >= NBUK;
    int nodeBase = (bucket - rel * NBUK) << 8;
    int bstart = soff[bucket * NBLK];
    int bend = (bucket == NBUK2 - 1) ? 2 * EE : soff[(bucket + 1) * NBLK];
    int tid = threadIdx.x;
    __shared__ int deg[256], sc[256];
    deg[tid] = 0;
    __syncthreads();
    for (int i = bstart + tid; i < bend; i += 256) {
        int d = (int)(staging[i] >> 32) & 255;
        atomicAdd(&deg[d], 1);
    }
    __syncthreads();
    int dv = deg[tid];
    sc[tid] = dv;
    __syncthreads();
    for (int off = 1; off < 256; off <<= 1) {
        int u = (tid >= off) ? sc[tid - off] : 0;
        __syncthreads();
        sc[tid] += u;
        __syncthreads();
    }
    int lrp = sc[tid] - dv;  // bucket-local exclusive prefix
    int nCount = min(256, NN - nodeBase);
    int relbase = rel ? EE : 0;
    if (tid < nCount) (rel ? rpN : rpP)[nodeBase + tid] = bstart - relbase + lrp;
    if (bucket == NBUK - 1 && tid == 0) rpP[NN] = EE;
    if (bucket == NBUK2 - 1 && tid == 0) rpN[NN] = EE;
    deg[tid] = lrp;          // reuse as cursor
    __syncthreads();
    for (int i = bstart + tid; i < bend; i += 256) {
        unsigned long long v = staging[i];
        int d = (int)(v >> 32) & 255;
        int src = (int)(v & 0xffffffffu);
        int slot = atomicAdd(&deg[d], 1);
        csrAll[bstart + slot] = src;
    }
}

// ---- pre-transform 64->32 x3: xp=x@Wp, xn=x@Wn, xs=x@Ws ----
__global__ __launch_bounds__(256) void k_xf1(const float* __restrict__ x,
                                             const float* __restrict__ Wp,
                                             const float* __restrict__ Wn,
                                             const float* __restrict__ Ws,
                                             float* __restrict__ xp,
                                             float* __restrict__ xn,
                                             float* __restrict__ xs) {
    __shared__ float sWp[64 * 32], sWn[64 * 32], sWs[64 * 32];
    for (int i = threadIdx.x; i < 64 * 32; i += 256) { sWp[i] = Wp[i]; sWn[i] = Wn[i]; sWs[i] = Ws[i]; }
    __syncthreads();
    int lane = threadIdx.x & 63;
    int j = lane & 31;
    int half = lane >> 5;
    int wid = (blockIdx.x * 256 + threadIdx.x) >> 6;
    const int nw = (2048 * 256) >> 6;
    for (int p = wid; 2 * p < NN; p += nw) {
        int n = 2 * p + half;
        float vlo = x[(size_t)n * 64 + j];
        float vhi = x[(size_t)n * 64 + 32 + j];
        float ap = 0.f, an = 0.f, as = 0.f;
        #pragma unroll
        for (int k = 0; k < 64; k++) {
            float xv = (k < 32) ? __shfl(vlo, k, 32) : __shfl(vhi, k - 32, 32);
            ap += xv * sWp[k * 32 + j];
            an += xv * sWn[k * 32 + j];
            as += xv * sWs[k * 32 + j];
        }
        xp[(size_t)n * 32 + j] = ap;
        xn[(size_t)n * 32 + j] = an;
        xs[(size_t)n * 32 + j] = as;
    }
}

// ---- pre-transform 32->32 x3 ----
__global__ __launch_bounds__(256) void k_xf2(const float* __restrict__ z,
                                             const float* __restrict__ Wp,
                                             const float* __restrict__ Wn,
                                             const float* __restrict__ Ws,
                                             float* __restrict__ xp,
                                             float* __restrict__ xn,
                                             float* __restrict__ xs) {
    __shared__ float sWp[32 * 32], sWn[32 * 32], sWs[32 * 32];
    for (int i = threadIdx.x; i < 32 * 32; i += 256) { sWp[i] = Wp[i]; sWn[i] = Wn[i]; sWs[i] = Ws[i]; }
    __syncthreads();
    int lane = threadIdx.x & 63;
    int j = lane & 31;
    int half = lane >> 5;
    int wid = (blockIdx.x * 256 + threadIdx.x) >> 6;
    const int nw = (2048 * 256) >> 6;
    for (int p = wid; 2 * p < NN; p += nw) {
        int n = 2 * p + half;
        float v = z[(size_t)n * 32 + j];
        float ap = 0.f, an = 0.f, as = 0.f;
        #pragma unroll
        for (int k = 0; k < 32; k++) {
            float xv = __shfl(v, k, 32);
            ap += xv * sWp[k * 32 + j];
            an += xv * sWn[k * 32 + j];
            as += xv * sWs[k * 32 + j];
        }
        xp[(size_t)n * 32 + j] = ap;
        xn[(size_t)n * 32 + j] = an;
        xs[(size_t)n * 32 + j] = as;
    }
}

// ---- accumulate one relation's neighbors ----
__device__ __forceinline__ float pull_rel(const float* __restrict__ xsrc,
                                          const int* __restrict__ csr,
                                          int b0, int b1, int j, float acc) {
    for (int base = b0; base < b1; base += 32) {
        int rem = b1 - base;
        int cnt = min(rem, 32);
        int idx = (j < rem) ? csr[base + j] : 0;
        int i = 0;
        for (; i + 4 <= cnt; i += 4) {
            int s0 = __shfl(idx, i, 32);
            int s1 = __shfl(idx, i + 1, 32);
            int s2 = __shfl(idx, i + 2, 32);
            int s3 = __shfl(idx, i + 3, 32);
            float v0 = xsrc[(size_t)s0 * 32 + j];
            float v1 = xsrc[(size_t)s1 * 32 + j];
            float v2 = xsrc[(size_t)s2 * 32 + j];
            float v3 = xsrc[(size_t)s3 * 32 + j];
            acc += v0; acc += v1; acc += v2; acc += v3;
        }
        for (; i < cnt; i++) {
            int s = __shfl(idx, i, 32);
            acc += xsrc[(size_t)s * 32 + j];
        }
    }
    return acc;
}

// ---- pull aggregation + combine + tanh ----
__global__ __launch_bounds__(256) void k_pull(const float* __restrict__ xp,
                                              const float* __restrict__ xn,
                                              const float* __restrict__ xs,
                                              const int* __restrict__ rpP,
                                              const int* __restrict__ csrP,
                                              const int* __restrict__ rpN,
                                              const int* __restrict__ csrN,
                                              const float* __restrict__ bp,
                                              const float* __restrict__ bn,
                                              const float* __restrict__ bs,
                                              float* __restrict__ out) {
    int j = threadIdx.x & 31;
    int hw = (blockIdx.x * 256 + threadIdx.x) >> 5;
    const int nhw = (2048 * 256) >> 5;
    float bpj = bp[j], bnj = bn[j], bsj = bs[j];
    for (int n = hw; n < NN; n += nhw) {
        int p0 = rpP[n], p1 = rpP[n + 1];
        int n0 = rpN[n], n1 = rpN[n + 1];
        float acc = xs[(size_t)n * 32 + j] + bsj
                  + (float)(p1 - p0) * bpj + (float)(n1 - n0) * bnj;
        acc = pull_rel(xp, csrP, p0, p1, j, acc);
        acc = pull_rel(xn, csrN, n0, n1, j, acc);
        out[(size_t)n * 32 + j] = tanhf(acc);
    }
}

// ---- fused tiled GEMM: z = tanh(z2@Wl + bl) [N,64], t1 = z@W1 + b1, BN stats ----
// one block per 64-node tile; lane = output col; W cols in VGPRs; X via LDS broadcast
__global__ __launch_bounds__(256) void k_wlin_mlp1(const float* __restrict__ z2,
                                                   const float* __restrict__ Wl,
                                                   const float* __restrict__ bl,
                                                   const float* __restrict__ W1,
                                                   const float* __restrict__ b1_,
                                                   float* __restrict__ z,
                                                   float* __restrict__ t1,
                                                   float* __restrict__ colsum,
                                                   float* __restrict__ colsq) {
    __shared__ float sx[64 * 32];   // z2 tile
    __shared__ float sz[64 * 64];   // z-row bounce buffer
    int base = blockIdx.x * 64;
    int tid = threadIdx.x;
    int lane = tid & 63;
    int wv = tid >> 6;
    // stage z2 tile: 64 rows x 32 cols, coalesced float4; zero OOB rows
    {
        int row = tid >> 2, c4 = tid & 3;   // 4 threads/row, 2 float4 each
        int n = base + row;
        #pragma unroll
        for (int m = 0; m < 2; m++) {
            int f = c4 + 4 * m;             // float4 index 0..7
            float4 v = (n < NN) ? *(const float4*)&z2[(size_t)n * 32 + f * 4]
                                : make_float4(0.f, 0.f, 0.f, 0.f);
            *(float4*)&sx[row * 32 + f * 4] = v;
        }
    }
    float wl[32];
    #pragma unroll
    for (int k = 0; k < 32; k++) wl[k] = Wl[k * 64 + lane];
    float w1[64];
    #pragma unroll
    for (int k = 0; k < 64; k++) w1[k] = W1[k * 64 + lane];
    float blj = bl[lane], b1j = b1_[lane];
    __syncthreads();
    float lsum = 0.f, lsq = 0.f;
    #pragma unroll 1
    for (int i = 0; i < 16; i++) {
        int nl = i * 4 + wv;
        int n = base + nl;
        float a0 = 0.f, a1c = 0.f, a2 = 0.f, a3 = 0.f;
        #pragma unroll
        for (int q = 0; q < 8; q++) {
            float4 xv = *(const float4*)&sx[nl * 32 + q * 4];
            a0 += xv.x * wl[q * 4 + 0];
            a1c += xv.y * wl[q * 4 + 1];
            a2 += xv.z * wl[q * 4 + 2];
            a3 += xv.w * wl[q * 4 + 3];
        }
        float zv = tanhf(blj + ((a0 + a1c) + (a2 + a3)));
        if (n < NN) z[(size_t)n * 64 + lane] = zv;
        sz[nl * 64 + lane] = zv;            // same-wave bounce (no barrier needed)
        float t0 = 0.f, t1a = 0.f, t2a = 0.f, t3a = 0.f;
        #pragma unroll
        for (int q = 0; q < 16; q++) {
            float4 zv4 = *(const float4*)&sz[nl * 64 + q * 4];
            t0 += zv4.x * w1[q * 4 + 0];
            t1a += zv4.y * w1[q * 4 + 1];
            t2a += zv4.z * w1[q * 4 + 2];
            t3a += zv4.w * w1[q * 4 + 3];
        }
        float t = b1j + ((t0 + t1a) + (t2a + t3a));
        if (n < NN) {
            t1[(size_t)n * 64 + lane] = t;
            lsum += t; lsq += t * t;
        }
    }
    __shared__ float red[256], red2[256];
    red[tid] = lsum; red2[tid] = lsq;
    __syncthreads();
    if (tid < 64) {
        float a = red[tid] + red[tid + 64] + red[tid + 128] + red[tid + 192];
        float q = red2[tid] + red2[tid + 64] + red2[tid + 128] + red2[tid + 192];
        fatomic(&colsum[tid], a);
        fatomic(&colsq[tid], q);
    }
}

// ---- BN stats -> affine coefficients a, c (h_norm = t*a + c) ----
__global__ void k_bnstats(const float* __restrict__ colsum, const float* __restrict__ colsq,
                          const float* __restrict__ g, const float* __restrict__ beta,
                          float* __restrict__ a, float* __restrict__ c) {
    int j = threadIdx.x;
    if (j < 64) {
        float m = colsum[j] * (1.f / NN);
        float v = colsq[j] * (1.f / NN) - m * m;
        float aj = g[j] * rsqrtf(v + EPSF);
        a[j] = aj;
        c[j] = beta[j] - m * aj;
    }
}

// ---- tiled GEMM: t2 = relu(t1*a1+c1) @ m2_W + m2_b, BN stats (BN+ReLU fused into staging) ----
__global__ __launch_bounds__(256) void k_mlp2(const float* __restrict__ t1,
                                              const float* __restrict__ a1,
                                              const float* __restrict__ c1,
                                              const float* __restrict__ W,
                                              const float* __restrict__ b,
                                              float* __restrict__ t2,
                                              float* __restrict__ colsum,
                                              float* __restrict__ colsq) {
    __shared__ float sh[64 * 64];   // h tile = relu(t1*a+c)
    int base = blockIdx.x * 64;
    int tid = threadIdx.x;
    int lane = tid & 63;
    int wv = tid >> 6;
    {
        int row = tid >> 2, c4 = tid & 3;   // 4 threads/row, 4 float4 each
        int n = base + row;
        #pragma unroll
        for (int m = 0; m < 4; m++) {
            int f = c4 + 4 * m;             // float4 index 0..15
            float4 tv = (n < NN) ? *(const float4*)&t1[(size_t)n * 64 + f * 4]
                                 : make_float4(0.f, 0.f, 0.f, 0.f);
            float4 av = *(const float4*)&a1[f * 4];
            float4 cv = *(const float4*)&c1[f * 4];
            float4 hv;
            hv.x = fmaxf(tv.x * av.x + cv.x, 0.f);
            hv.y = fmaxf(tv.y * av.y + cv.y, 0.f);
            hv.z = fmaxf(tv.z * av.z + cv.z, 0.f);
            hv.w = fmaxf(tv.w * av.w + cv.w, 0.f);
            *(float4*)&sh[row * 64 + f * 4] = hv;
        }
    }
    float w[64];
    #pragma unroll
    for (int k = 0; k < 64; k++) w[k] = W[k * 64 + lane];
    float bj = b[lane];
    __syncthreads();
    float lsum = 0.f, lsq = 0.f;
    #pragma unroll 1
    for (int i = 0; i < 16; i++) {
        int nl = i * 4 + wv;
        int n = base + nl;
        float a0 = 0.f, a1c = 0.f, a2 = 0.f, a3 = 0.f;
        #pragma unroll
        for (int q = 0; q < 16; q++) {
            float4 xv = *(const float4*)&sh[nl * 64 + q * 4];
            a0 += xv.x * w[q * 4 + 0];
            a1c += xv.y * w[q * 4 + 1];
            a2 += xv.z * w[q * 4 + 2];
            a3 += xv.w * w[q * 4 + 3];
        }
        float s = bj + ((a0 + a1c) + (a2 + a3));
        if (n < NN) {
            t2[(size_t)n * 64 + lane] = s;
            lsum += s; lsq += s * s;
        }
    }
    __shared__ float red[256], red2[256];
    red[tid] = lsum; red2[tid] = lsq;
    __syncthreads();
    if (tid < 64) {
        float a = red[tid] + red[tid + 64] + red[tid + 128] + red[tid + 192];
        float q = red2[tid] + red2[tid + 64] + red2[tid + 128] + red2[tid + 192];
        fatomic(&colsum[tid], a);
        fatomic(&colsq[tid], q);
    }
}

// ---- prob = sigmoid(relu(t2*a2+c2) @ m3_W + m3_b) ----
__global__ __launch_bounds__(256) void k_mlp3(const float* __restrict__ t2,
                                              const float* __restrict__ a2,
                                              const float* __restrict__ c2,
                                              const float* __restrict__ W3,
                                              const float* __restrict__ b3,
                                              float* __restrict__ prob) {
    int j = threadIdx.x & 63;
    int r = threadIdx.x >> 6;
    float aj = a2[j], cj = c2[j], wj = W3[j], bb = b3[0];
    for (int n = blockIdx.x * 4 + r; n < NN; n += 2048 * 4) {
        float h = fmaxf(t2[(size_t)n * 64 + j] * aj + cj, 0.f) * wj;
        #pragma unroll
        for (int off = 32; off > 0; off >>= 1) h += __shfl_xor(h, off, 64);
        if (j == 0) prob[n] = 1.f / (1.f + expf(-(h + bb)));
    }
}

extern "C" void kernel_launch(void* const* d_in, const int* in_sizes, int n_in,
                              void* d_out, int out_size, void* d_ws, size_t ws_size,
                              hipStream_t stream) {
    const float* init_emb = (const float*)d_in[0];
    const int* pe = (const int*)d_in[1];
    const int* ne = (const int*)d_in[2];
    const float* c1_Wp = (const float*)d_in[3];  const float* c1_bp = (const float*)d_in[4];
    const float* c1_Wn = (const float*)d_in[5];  const float* c1_bn = (const float*)d_in[6];
    const float* c1_Ws = (const float*)d_in[7];  const float* c1_bs = (const float*)d_in[8];
    const float* c2_Wp = (const float*)d_in[9];  const float* c2_bp = (const float*)d_in[10];
    const float* c2_Wn = (const float*)d_in[11]; const float* c2_bn = (const float*)d_in[12];
    const float* c2_Ws = (const float*)d_in[13]; const float* c2_bs = (const float*)d_in[14];
    const float* w_W = (const float*)d_in[15];   const float* w_b = (const float*)d_in[16];
    const float* m1_W = (const float*)d_in[17];  const float* m1_b = (const float*)d_in[18];
    const float* g1 = (const float*)d_in[19];    const float* b1 = (const float*)d_in[20];
    const float* m2_W = (const float*)d_in[21];  const float* m2_b = (const float*)d_in[22];
    const float* g2 = (const float*)d_in[23];    const float* b2 = (const float*)d_in[24];
    const float* m3_W = (const float*)d_in[25];  const float* m3_b = (const float*)d_in[26];

    // ---- workspace arena ----
    size_t off = 0;
    auto alloc = [&](size_t bytes) -> void* {
        void* r = (char*)d_ws + off;
        off += (bytes + 255) & ~(size_t)255;
        return r;
    };
    // zero region (front): only BN stat accumulators
    float* sums = (float*)alloc(256 * 4);               // colsum1, colsq1, colsum2, colsq2
    size_t zero_bytes = off;
    // CSR-build region (dead after second k_pull; t2 aliases it later)
    size_t csr_region = off;
    int*   hist = (int*)alloc((size_t)NBUK2 * NBLK * 4);        // 800KB
    int*   soff = (int*)alloc((size_t)NBUK2 * NBLK * 4);        // 800KB
    int*   part = (int*)alloc((size_t)1024 * 4);
    unsigned long long* staging = (unsigned long long*)alloc((size_t)2 * EE * 8);  // 16MB
    int*   csrAll = (int*)alloc((size_t)2 * EE * 4);            // 8MB
    // persistent
    int*   rpP  = (int*)alloc((size_t)(NN + 1) * 4);
    int*   rpN  = (int*)alloc((size_t)(NN + 1) * 4);
    float* R1   = (float*)alloc((size_t)NN * 96 * 4);   // {xp,xn,xs} layer1 -> layer2 -> t1
    float* z1   = (float*)alloc((size_t)NN * 32 * 4);
    float* z2   = (float*)alloc((size_t)NN * 32 * 4);
    float* abc  = (float*)alloc(256 * 4);               // a1, c1, a2, c2

    int* csrP = csrAll;
    int* csrN = csrAll + (size_t)EE;
    float* xp = R1;
    float* xn = R1 + (size_t)NN * 32;
    float* xs = R1 + (size_t)NN * 64;
    float* t1 = R1;                                     // dead xp/xn region after wlin
    float* t2 = (float*)((char*)d_ws + csr_region);     // aliases CSR-build scratch (25.6MB fits)

    float* z_out = (float*)d_out;                       // [N,64]
    float* prob  = (float*)d_out + (size_t)NN * 64;     // [N,1]

    hipMemsetAsync(d_ws, 0, zero_bytes, stream);

    // ---- CSR build: hist -> scan -> bin scatter -> per-bucket local build ----
    k_hist<<<NBLK, 256, 0, stream>>>(pe, ne, hist);
    k_gscan1<<<GSB, 256, 0, stream>>>(hist, soff, part);
    k_gscan2<<<1, 1024, 0, stream>>>(part);
    k_gscan3<<<GSB, 256, 0, stream>>>(part, soff);
    k_binscatter<<<NBLK, 256, 0, stream>>>(pe, ne, soff, staging);
    k_local<<<NBUK2, 256, 0, stream>>>(staging, soff, rpP, rpN, csrAll);

    // layer 1
    k_xf1<<<2048, 256, 0, stream>>>(init_emb, c1_Wp, c1_Wn, c1_Ws, xp, xn, xs);
    k_pull<<<2048, 256, 0, stream>>>(xp, xn, xs, rpP, csrP, rpN, csrN, c1_bp, c1_bn, c1_bs, z1);
    // layer 2
    k_xf2<<<2048, 256, 0, stream>>>(z1, c2_Wp, c2_Wn, c2_Ws, xp, xn, xs);
    k_pull<<<2048, 256, 0, stream>>>(xp, xn, xs, rpP, csrP, rpN, csrN, c2_bp, c2_bn, c2_bs, z2);
    // readout
    k_wlin_mlp1<<<GTILES, 256, 0, stream>>>(z2, w_W, w_b, m1_W, m1_b, z_out, t1, sums + 0, sums + 64);
    k_bnstats<<<1, 64, 0, stream>>>(sums + 0, sums + 64, g1, b1, abc + 0, abc + 64);
    k_mlp2<<<GTILES, 256, 0, stream>>>(t1, abc + 0, abc + 64, m2_W, m2_b, t2, sums + 128, sums + 192);
    k_bnstats<<<1, 64, 0, stream>>>(sums + 128, sums + 192, g2, b2, abc + 128, abc + 192);
    k_mlp3<<<2048, 256, 0, stream>>>(t2, abc + 128, abc + 192, m3_W, m3_b, prob);
}